// Round 1
// baseline (1305.015 us; speedup 1.0000x reference)
//
#include <hip/hip_runtime.h>
#include <math.h>

// Problem constants (from reference)
#define B_ 4
#define L_ 2048
#define R_ 1024
#define D_ 128      // ssm input dim
#define N_ 64       // state size
#define TWO_D 256   // 2*D
#define M_ (B_*L_)  // 8192 rows

__device__ __forceinline__ float silu_f(float z) {
    return z / (1.0f + __expf(-z));
}

__device__ __forceinline__ float softplus_f(float z) {
    // numerically stable softplus
    return fmaxf(z, 0.0f) + log1pf(__expf(-fabsf(z)));
}

// ---------------------------------------------------------------------------
// Kernel 1: u = up_x @ W_up + b_up   [8192,1024] @ [1024,256] -> [8192,256]
// Tiled fp32 GEMM: BM=64, BN=64, BK=16, 256 threads, 4x4 per thread.
// ---------------------------------------------------------------------------
__global__ __launch_bounds__(256) void gemm_up_kernel(
    const float* __restrict__ A,   // [M,K] row-major
    const float* __restrict__ W,   // [K,N] row-major
    const float* __restrict__ bias,
    float* __restrict__ C,
    int M, int N, int Kd)
{
    __shared__ float As[16][65];   // [k][m], padded
    __shared__ float Bs[16][64];   // [k][n]

    int tid = threadIdx.x;
    int bm = blockIdx.y, bn = blockIdx.x;
    int tx = tid & 15, ty = tid >> 4;

    float acc[4][4];
    #pragma unroll
    for (int i = 0; i < 4; i++)
        #pragma unroll
        for (int j = 0; j < 4; j++) acc[i][j] = 0.0f;

    for (int kt = 0; kt < Kd; kt += 16) {
        #pragma unroll
        for (int i = 0; i < 4; i++) {
            int idx = tid + i * 256;
            int m = idx >> 4, kk = idx & 15;
            As[kk][m] = A[(size_t)(bm * 64 + m) * Kd + kt + kk];
        }
        #pragma unroll
        for (int i = 0; i < 4; i++) {
            int idx = tid + i * 256;
            int kk = idx >> 6, nn = idx & 63;
            Bs[kk][nn] = W[(size_t)(kt + kk) * N + bn * 64 + nn];
        }
        __syncthreads();
        #pragma unroll
        for (int kk = 0; kk < 16; kk++) {
            float a[4], bv[4];
            #pragma unroll
            for (int i = 0; i < 4; i++) a[i] = As[kk][ty * 4 + i];
            #pragma unroll
            for (int j = 0; j < 4; j++) bv[j] = Bs[kk][tx * 4 + j];
            #pragma unroll
            for (int i = 0; i < 4; i++)
                #pragma unroll
                for (int j = 0; j < 4; j++)
                    acc[i][j] = fmaf(a[i], bv[j], acc[i][j]);
        }
        __syncthreads();
    }

    #pragma unroll
    for (int i = 0; i < 4; i++) {
        int row = bm * 64 + ty * 4 + i;
        #pragma unroll
        for (int j = 0; j < 4; j++) {
            int col = bn * 64 + tx * 4 + j;
            C[(size_t)row * N + col] = acc[i][j] + bias[col];
        }
    }
}

// ---------------------------------------------------------------------------
// Kernel 2: causal depthwise conv K=3 + SiLU
// x[b,t,c] = silu( w0*left[t-2] + w1*left[t-1] + w2*left[t] + cb )
// left = u[..., 0:D]
// ---------------------------------------------------------------------------
__global__ __launch_bounds__(256) void conv_silu_kernel(
    const float* __restrict__ u,      // [M, 2D]
    const float* __restrict__ conv_w, // [D,3]
    const float* __restrict__ conv_b, // [D]
    float* __restrict__ x)            // [M, D]
{
    int idx = blockIdx.x * 256 + threadIdx.x;   // over M*D
    if (idx >= M_ * D_) return;
    int r = idx >> 7;        // row in [0,M)
    int c = idx & 127;       // channel
    int t = r & (L_ - 1);    // position within sequence (L=2048 pow2)

    float w0 = conv_w[c * 3 + 0];
    float w1 = conv_w[c * 3 + 1];
    float w2 = conv_w[c * 3 + 2];

    float v2 = u[(size_t)r * TWO_D + c];
    float v1 = (t >= 1) ? u[(size_t)(r - 1) * TWO_D + c] : 0.0f;
    float v0 = (t >= 2) ? u[(size_t)(r - 2) * TWO_D + c] : 0.0f;

    float z = fmaf(w0, v0, fmaf(w1, v1, fmaf(w2, v2, conv_b[c])));
    x[idx] = silu_f(z);
}

// ---------------------------------------------------------------------------
// Kernel 3: delta = softplus(x@W_delta + b_delta); Bm = x@W_B + b_B; Cm = x@W_C + b_C
// One block (256 threads) per row. Waves specialize: w0,w1 -> delta, w2 -> B, w3 -> C.
// ---------------------------------------------------------------------------
__global__ __launch_bounds__(256) void proj_kernel(
    const float* __restrict__ x,       // [M,D]
    const float* __restrict__ W_delta, const float* __restrict__ b_delta,
    const float* __restrict__ W_B,     const float* __restrict__ b_B,
    const float* __restrict__ W_C,     const float* __restrict__ b_C,
    float* __restrict__ delta,         // [M,D]
    float* __restrict__ Bm,            // [M,N]
    float* __restrict__ Cm)            // [M,N]
{
    __shared__ float xs[128];
    int r = blockIdx.x;
    int tid = threadIdx.x;
    if (tid < 128) xs[tid] = x[(size_t)r * D_ + tid];
    __syncthreads();

    if (tid < 128) {
        int j = tid;
        float acc = b_delta[j];
        #pragma unroll 8
        for (int k = 0; k < 128; k++)
            acc = fmaf(xs[k], W_delta[k * 128 + j], acc);
        delta[(size_t)r * D_ + j] = softplus_f(acc);
    } else if (tid < 192) {
        int n = tid - 128;
        float acc = b_B[n];
        #pragma unroll 8
        for (int k = 0; k < 128; k++)
            acc = fmaf(xs[k], W_B[k * 64 + n], acc);
        Bm[(size_t)r * N_ + n] = acc;
    } else {
        int n = tid - 192;
        float acc = b_C[n];
        #pragma unroll 8
        for (int k = 0; k < 128; k++)
            acc = fmaf(xs[k], W_C[k * 64 + n], acc);
        Cm[(size_t)r * N_ + n] = acc;
    }
}

// ---------------------------------------------------------------------------
// Kernel 4: selective scan. One wave per (b,d), lane = n.
// h_t = exp(delta_t * A[d,n]) * h_{t-1} + delta_t * B_t[n] * x_t
// y_t[d] = sum_n h_t[n]*C_t[n] + D_skip[d]*x_t
// ---------------------------------------------------------------------------
__global__ __launch_bounds__(256) void scan_kernel(
    const float* __restrict__ delta,  // [M,D]
    const float* __restrict__ x,      // [M,D]
    const float* __restrict__ Bm,     // [M,N]
    const float* __restrict__ Cm,     // [M,N]
    const float* __restrict__ A_log,  // [D,N]
    const float* __restrict__ D_skip, // [D]
    float* __restrict__ y)            // [M,D]
{
    int w = blockIdx.x * 4 + (threadIdx.x >> 6);  // 0..511
    int b = w >> 7;
    int d = w & 127;
    int n = threadIdx.x & 63;

    float A_dn = -__expf(A_log[d * N_ + n]);
    float dsk = D_skip[d];

    const float* dp = delta + (size_t)b * L_ * D_ + d;
    const float* xp = x     + (size_t)b * L_ * D_ + d;
    const float* bp = Bm    + (size_t)b * L_ * N_ + n;
    const float* cp = Cm    + (size_t)b * L_ * N_ + n;
    float*       yp = y     + (size_t)b * L_ * D_ + d;

    float h = 0.0f;
    for (int t = 0; t < L_; t++) {
        float dl = dp[(size_t)t * D_];
        float xv = xp[(size_t)t * D_];
        float bv = bp[(size_t)t * N_];
        float cv = cp[(size_t)t * N_];
        float dA = __expf(dl * A_dn);
        h = fmaf(dA, h, dl * bv * xv);
        float p = h * cv;
        #pragma unroll
        for (int off = 32; off >= 1; off >>= 1)
            p += __shfl_xor(p, off, 64);
        if (n == 0) yp[(size_t)t * D_] = fmaf(dsk, xv, p);
    }
}

// ---------------------------------------------------------------------------
// Kernel 5: out = (y * silu(u_right)) @ W_down + b_down
// Same tiled GEMM, gating fused into A-tile staging. M=8192, N=1024, K=128.
// ---------------------------------------------------------------------------
__global__ __launch_bounds__(256) void gemm_down_kernel(
    const float* __restrict__ y,     // [M,D]
    const float* __restrict__ u,     // [M,2D] (right half gates)
    const float* __restrict__ W,     // [D,N] row-major
    const float* __restrict__ bias,  // [N]
    float* __restrict__ out,         // [M,N]
    int M, int N, int Kd)
{
    __shared__ float As[16][65];
    __shared__ float Bs[16][64];

    int tid = threadIdx.x;
    int bm = blockIdx.y, bn = blockIdx.x;
    int tx = tid & 15, ty = tid >> 4;

    float acc[4][4];
    #pragma unroll
    for (int i = 0; i < 4; i++)
        #pragma unroll
        for (int j = 0; j < 4; j++) acc[i][j] = 0.0f;

    for (int kt = 0; kt < Kd; kt += 16) {
        #pragma unroll
        for (int i = 0; i < 4; i++) {
            int idx = tid + i * 256;
            int m = idx >> 4, kk = idx & 15;
            int row = bm * 64 + m;
            int k = kt + kk;
            float g = u[(size_t)row * TWO_D + D_ + k];
            As[kk][m] = y[(size_t)row * D_ + k] * silu_f(g);
        }
        #pragma unroll
        for (int i = 0; i < 4; i++) {
            int idx = tid + i * 256;
            int kk = idx >> 6, nn = idx & 63;
            Bs[kk][nn] = W[(size_t)(kt + kk) * N + bn * 64 + nn];
        }
        __syncthreads();
        #pragma unroll
        for (int kk = 0; kk < 16; kk++) {
            float a[4], bv[4];
            #pragma unroll
            for (int i = 0; i < 4; i++) a[i] = As[kk][ty * 4 + i];
            #pragma unroll
            for (int j = 0; j < 4; j++) bv[j] = Bs[kk][tx * 4 + j];
            #pragma unroll
            for (int i = 0; i < 4; i++)
                #pragma unroll
                for (int j = 0; j < 4; j++)
                    acc[i][j] = fmaf(a[i], bv[j], acc[i][j]);
        }
        __syncthreads();
    }

    #pragma unroll
    for (int i = 0; i < 4; i++) {
        int row = bm * 64 + ty * 4 + i;
        #pragma unroll
        for (int j = 0; j < 4; j++) {
            int col = bn * 64 + tx * 4 + j;
            out[(size_t)row * N + col] = acc[i][j] + bias[col];
        }
    }
}

// ---------------------------------------------------------------------------
extern "C" void kernel_launch(void* const* d_in, const int* in_sizes, int n_in,
                              void* d_out, int out_size, void* d_ws, size_t ws_size,
                              hipStream_t stream)
{
    const float* up_x    = (const float*)d_in[0];
    const float* W_up    = (const float*)d_in[1];
    const float* b_up    = (const float*)d_in[2];
    const float* conv_w  = (const float*)d_in[3];
    const float* conv_b  = (const float*)d_in[4];
    const float* W_delta = (const float*)d_in[5];
    const float* b_delta = (const float*)d_in[6];
    const float* W_B     = (const float*)d_in[7];
    const float* b_B     = (const float*)d_in[8];
    const float* W_C     = (const float*)d_in[9];
    const float* b_C     = (const float*)d_in[10];
    const float* A_log   = (const float*)d_in[11];
    const float* D_skip  = (const float*)d_in[12];
    const float* W_down  = (const float*)d_in[13];
    const float* b_down  = (const float*)d_in[14];

    float* out = (float*)d_out;
    float* ws  = (float*)d_ws;

    // workspace layout (floats)
    float* u     = ws;                  // M*2D = 2,097,152
    float* x     = u + (size_t)M_ * TWO_D;     // M*D = 1,048,576
    float* delta = x + (size_t)M_ * D_;        // M*D
    float* Bm    = delta + (size_t)M_ * D_;    // M*N = 524,288
    float* Cm    = Bm + (size_t)M_ * N_;       // M*N
    float* y     = Cm + (size_t)M_ * N_;       // M*D

    // 1. up-projection GEMM
    gemm_up_kernel<<<dim3(TWO_D / 64, M_ / 64), 256, 0, stream>>>(
        up_x, W_up, b_up, u, M_, TWO_D, R_);

    // 2. causal conv + silu
    conv_silu_kernel<<<(M_ * D_ + 255) / 256, 256, 0, stream>>>(
        u, conv_w, conv_b, x);

    // 3. delta/B/C projections
    proj_kernel<<<M_, 256, 0, stream>>>(
        x, W_delta, b_delta, W_B, b_B, W_C, b_C, delta, Bm, Cm);

    // 4. selective scan
    scan_kernel<<<(B_ * D_) / 4, 256, 0, stream>>>(
        delta, x, Bm, Cm, A_log, D_skip, y);

    // 5. gate + down-projection GEMM
    gemm_down_kernel<<<dim3(R_ / 64, M_ / 64), 256, 0, stream>>>(
        y, u, W_down, b_down, out, M_, R_, D_);
}

// Round 2
// 491.907 us; speedup vs baseline: 2.6530x; 2.6530x over previous
//
#include <hip/hip_runtime.h>
#include <math.h>

// Problem constants (from reference)
#define B_ 4
#define L_ 2048
#define R_ 1024
#define D_ 128      // ssm input dim
#define N_ 64       // state size
#define TWO_D 256   // 2*D
#define M_ (B_*L_)  // 8192 rows
#define TC 128      // scan chunk length
#define NC (L_/TC)  // 16 chunks per sequence

__device__ __forceinline__ float silu_f(float z) {
    return z / (1.0f + __expf(-z));
}

__device__ __forceinline__ float softplus_f(float z) {
    return fmaxf(z, 0.0f) + log1pf(__expf(-fabsf(z)));
}

// ---------------------------------------------------------------------------
// Kernel 1: u = up_x @ W_up + b_up   [8192,1024] @ [1024,256] -> [8192,256]
// ---------------------------------------------------------------------------
__global__ __launch_bounds__(256) void gemm_up_kernel(
    const float* __restrict__ A,
    const float* __restrict__ W,
    const float* __restrict__ bias,
    float* __restrict__ C,
    int M, int N, int Kd)
{
    __shared__ float As[16][65];
    __shared__ float Bs[16][64];

    int tid = threadIdx.x;
    int bm = blockIdx.y, bn = blockIdx.x;
    int tx = tid & 15, ty = tid >> 4;

    float acc[4][4];
    #pragma unroll
    for (int i = 0; i < 4; i++)
        #pragma unroll
        for (int j = 0; j < 4; j++) acc[i][j] = 0.0f;

    for (int kt = 0; kt < Kd; kt += 16) {
        #pragma unroll
        for (int i = 0; i < 4; i++) {
            int idx = tid + i * 256;
            int m = idx >> 4, kk = idx & 15;
            As[kk][m] = A[(size_t)(bm * 64 + m) * Kd + kt + kk];
        }
        #pragma unroll
        for (int i = 0; i < 4; i++) {
            int idx = tid + i * 256;
            int kk = idx >> 6, nn = idx & 63;
            Bs[kk][nn] = W[(size_t)(kt + kk) * N + bn * 64 + nn];
        }
        __syncthreads();
        #pragma unroll
        for (int kk = 0; kk < 16; kk++) {
            float a[4], bv[4];
            #pragma unroll
            for (int i = 0; i < 4; i++) a[i] = As[kk][ty * 4 + i];
            #pragma unroll
            for (int j = 0; j < 4; j++) bv[j] = Bs[kk][tx * 4 + j];
            #pragma unroll
            for (int i = 0; i < 4; i++)
                #pragma unroll
                for (int j = 0; j < 4; j++)
                    acc[i][j] = fmaf(a[i], bv[j], acc[i][j]);
        }
        __syncthreads();
    }

    #pragma unroll
    for (int i = 0; i < 4; i++) {
        int row = bm * 64 + ty * 4 + i;
        #pragma unroll
        for (int j = 0; j < 4; j++) {
            int col = bn * 64 + tx * 4 + j;
            C[(size_t)row * N + col] = acc[i][j] + bias[col];
        }
    }
}

// ---------------------------------------------------------------------------
// Kernel 2: causal depthwise conv K=3 + SiLU
// ---------------------------------------------------------------------------
__global__ __launch_bounds__(256) void conv_silu_kernel(
    const float* __restrict__ u,
    const float* __restrict__ conv_w,
    const float* __restrict__ conv_b,
    float* __restrict__ x)
{
    int idx = blockIdx.x * 256 + threadIdx.x;
    if (idx >= M_ * D_) return;
    int r = idx >> 7;
    int c = idx & 127;
    int t = r & (L_ - 1);

    float w0 = conv_w[c * 3 + 0];
    float w1 = conv_w[c * 3 + 1];
    float w2 = conv_w[c * 3 + 2];

    float v2 = u[(size_t)r * TWO_D + c];
    float v1 = (t >= 1) ? u[(size_t)(r - 1) * TWO_D + c] : 0.0f;
    float v0 = (t >= 2) ? u[(size_t)(r - 2) * TWO_D + c] : 0.0f;

    float z = fmaf(w0, v0, fmaf(w1, v1, fmaf(w2, v2, conv_b[c])));
    x[idx] = silu_f(z);
}

// ---------------------------------------------------------------------------
// Kernel 3: delta/B/C projections (wave-specialized per output)
// ---------------------------------------------------------------------------
__global__ __launch_bounds__(256) void proj_kernel(
    const float* __restrict__ x,
    const float* __restrict__ W_delta, const float* __restrict__ b_delta,
    const float* __restrict__ W_B,     const float* __restrict__ b_B,
    const float* __restrict__ W_C,     const float* __restrict__ b_C,
    float* __restrict__ delta,
    float* __restrict__ Bm,
    float* __restrict__ Cm)
{
    __shared__ float xs[128];
    int r = blockIdx.x;
    int tid = threadIdx.x;
    if (tid < 128) xs[tid] = x[(size_t)r * D_ + tid];
    __syncthreads();

    if (tid < 128) {
        int j = tid;
        float acc = b_delta[j];
        #pragma unroll 8
        for (int k = 0; k < 128; k++)
            acc = fmaf(xs[k], W_delta[k * 128 + j], acc);
        delta[(size_t)r * D_ + j] = softplus_f(acc);
    } else if (tid < 192) {
        int n = tid - 128;
        float acc = b_B[n];
        #pragma unroll 8
        for (int k = 0; k < 128; k++)
            acc = fmaf(xs[k], W_B[k * 64 + n], acc);
        Bm[(size_t)r * N_ + n] = acc;
    } else {
        int n = tid - 192;
        float acc = b_C[n];
        #pragma unroll 8
        for (int k = 0; k < 128; k++)
            acc = fmaf(xs[k], W_C[k * 64 + n], acc);
        Cm[(size_t)r * N_ + n] = acc;
    }
}

// ---------------------------------------------------------------------------
// Kernel 4a: chunked scan, pass A — local scan per (b,d,chunk), h_in = 0.
// Writes local y and per-chunk summary (prod dA, h_final) per state n.
// 8192 waves -> 32 waves/CU.
// ---------------------------------------------------------------------------
__global__ __launch_bounds__(256) void scan_chunk_kernel(
    const float* __restrict__ delta,   // [M,D]
    const float* __restrict__ x,       // [M,D]
    const float* __restrict__ Bm,      // [M,N]
    const float* __restrict__ Cm,      // [M,N]
    const float* __restrict__ A_log,   // [D,N]
    const float* __restrict__ D_skip,  // [D]
    float* __restrict__ y,             // [M,D]
    float* __restrict__ ch_aprod,      // [B,D,NC,N]
    float* __restrict__ ch_h)          // [B,D,NC,N]
{
    int w = blockIdx.x * 4 + (threadIdx.x >> 6);  // 0..B*D*NC-1
    int n = threadIdx.x & 63;
    int c = w & (NC - 1);
    int d = (w >> 4) & 127;       // NC=16 -> shift 4
    int b = w >> 11;              // 16*128 = 2048 -> shift 11

    float A_dn = -__expf(A_log[d * N_ + n]);
    float dsk = D_skip[d];

    size_t row0 = (size_t)b * L_ + c * TC;
    const float* dp = delta + row0 * D_ + d;
    const float* xp = x     + row0 * D_ + d;
    const float* bp = Bm    + row0 * N_ + n;
    const float* cp = Cm    + row0 * N_ + n;
    float*       yp = y     + row0 * D_ + d;

    float h = 0.0f;
    float ap = 1.0f;
    #pragma unroll 4
    for (int t = 0; t < TC; t++) {
        float dl = dp[t * D_];
        float xv = xp[t * D_];
        float bv = bp[t * N_];
        float cv = cp[t * N_];
        float dA = __expf(dl * A_dn);
        h = fmaf(dA, h, dl * bv * xv);
        ap *= dA;
        float p = h * cv;
        #pragma unroll
        for (int off = 32; off >= 1; off >>= 1)
            p += __shfl_xor(p, off, 64);
        if (n == 0) yp[t * D_] = fmaf(dsk, xv, p);
    }

    size_t ci = (((size_t)b * D_ + d) * NC + c) * N_ + n;
    ch_aprod[ci] = ap;
    ch_h[ci] = h;
}

// ---------------------------------------------------------------------------
// Kernel 4b: serial prefix over the 16 chunk summaries, per (b,d,n).
// h_in[c] = incoming state for chunk c.
// ---------------------------------------------------------------------------
__global__ __launch_bounds__(256) void scan_prefix_kernel(
    const float* __restrict__ ch_aprod,
    const float* __restrict__ ch_h,
    float* __restrict__ hin)           // [B,D,NC,N]
{
    int idx = blockIdx.x * 256 + threadIdx.x;   // over B*D*N
    if (idx >= B_ * D_ * N_) return;
    int n = idx & 63;
    int d = (idx >> 6) & 127;
    int b = idx >> 13;

    size_t base = (((size_t)b * D_ + d) * NC) * N_ + n;
    float h = 0.0f;
    #pragma unroll
    for (int c = 0; c < NC; c++) {
        hin[base + (size_t)c * N_] = h;
        h = fmaf(ch_aprod[base + (size_t)c * N_], h, ch_h[base + (size_t)c * N_]);
    }
}

// ---------------------------------------------------------------------------
// Kernel 4c: correction pass — add  sum_n (prod_{s<=t} dA_s) * h_in[n] * C_t[n]
// to y for chunks 1..NC-1. 7680 waves.
// ---------------------------------------------------------------------------
__global__ __launch_bounds__(256) void scan_fix_kernel(
    const float* __restrict__ delta,
    const float* __restrict__ Cm,
    const float* __restrict__ A_log,
    const float* __restrict__ hin,
    float* __restrict__ y)
{
    int w = blockIdx.x * 4 + (threadIdx.x >> 6);  // 0..B*D*(NC-1)-1
    int n = threadIdx.x & 63;
    int c = (w % (NC - 1)) + 1;      // 1..NC-1
    int rest = w / (NC - 1);
    int d = rest & 127;
    int b = rest >> 7;

    float A_dn = -__expf(A_log[d * N_ + n]);
    float hv = hin[(((size_t)b * D_ + d) * NC + c) * N_ + n];

    size_t row0 = (size_t)b * L_ + c * TC;
    const float* dp = delta + row0 * D_ + d;
    const float* cp = Cm    + row0 * N_ + n;
    float*       yp = y     + row0 * D_ + d;

    float ap = 1.0f;
    #pragma unroll 4
    for (int t = 0; t < TC; t++) {
        float dl = dp[t * D_];
        float cv = cp[t * N_];
        float dA = __expf(dl * A_dn);
        ap *= dA;
        float p = ap * hv * cv;
        #pragma unroll
        for (int off = 32; off >= 1; off >>= 1)
            p += __shfl_xor(p, off, 64);
        if (n == 0) yp[t * D_] += p;
    }
}

// ---------------------------------------------------------------------------
// Kernel 5: out = (y * silu(u_right)) @ W_down + b_down
// ---------------------------------------------------------------------------
__global__ __launch_bounds__(256) void gemm_down_kernel(
    const float* __restrict__ y,
    const float* __restrict__ u,
    const float* __restrict__ W,
    const float* __restrict__ bias,
    float* __restrict__ out,
    int M, int N, int Kd)
{
    __shared__ float As[16][65];
    __shared__ float Bs[16][64];

    int tid = threadIdx.x;
    int bm = blockIdx.y, bn = blockIdx.x;
    int tx = tid & 15, ty = tid >> 4;

    float acc[4][4];
    #pragma unroll
    for (int i = 0; i < 4; i++)
        #pragma unroll
        for (int j = 0; j < 4; j++) acc[i][j] = 0.0f;

    for (int kt = 0; kt < Kd; kt += 16) {
        #pragma unroll
        for (int i = 0; i < 4; i++) {
            int idx = tid + i * 256;
            int m = idx >> 4, kk = idx & 15;
            int row = bm * 64 + m;
            int k = kt + kk;
            float g = u[(size_t)row * TWO_D + D_ + k];
            As[kk][m] = y[(size_t)row * D_ + k] * silu_f(g);
        }
        #pragma unroll
        for (int i = 0; i < 4; i++) {
            int idx = tid + i * 256;
            int kk = idx >> 6, nn = idx & 63;
            Bs[kk][nn] = W[(size_t)(kt + kk) * N + bn * 64 + nn];
        }
        __syncthreads();
        #pragma unroll
        for (int kk = 0; kk < 16; kk++) {
            float a[4], bv[4];
            #pragma unroll
            for (int i = 0; i < 4; i++) a[i] = As[kk][ty * 4 + i];
            #pragma unroll
            for (int j = 0; j < 4; j++) bv[j] = Bs[kk][tx * 4 + j];
            #pragma unroll
            for (int i = 0; i < 4; i++)
                #pragma unroll
                for (int j = 0; j < 4; j++)
                    acc[i][j] = fmaf(a[i], bv[j], acc[i][j]);
        }
        __syncthreads();
    }

    #pragma unroll
    for (int i = 0; i < 4; i++) {
        int row = bm * 64 + ty * 4 + i;
        #pragma unroll
        for (int j = 0; j < 4; j++) {
            int col = bn * 64 + tx * 4 + j;
            out[(size_t)row * N + col] = acc[i][j] + bias[col];
        }
    }
}

// ---------------------------------------------------------------------------
extern "C" void kernel_launch(void* const* d_in, const int* in_sizes, int n_in,
                              void* d_out, int out_size, void* d_ws, size_t ws_size,
                              hipStream_t stream)
{
    const float* up_x    = (const float*)d_in[0];
    const float* W_up    = (const float*)d_in[1];
    const float* b_up    = (const float*)d_in[2];
    const float* conv_w  = (const float*)d_in[3];
    const float* conv_b  = (const float*)d_in[4];
    const float* W_delta = (const float*)d_in[5];
    const float* b_delta = (const float*)d_in[6];
    const float* W_B     = (const float*)d_in[7];
    const float* b_B     = (const float*)d_in[8];
    const float* W_C     = (const float*)d_in[9];
    const float* b_C     = (const float*)d_in[10];
    const float* A_log   = (const float*)d_in[11];
    const float* D_skip  = (const float*)d_in[12];
    const float* W_down  = (const float*)d_in[13];
    const float* b_down  = (const float*)d_in[14];

    float* out = (float*)d_out;
    float* ws  = (float*)d_ws;

    // workspace layout (floats)
    float* u        = ws;                          // M*2D   = 2,097,152
    float* x        = u + (size_t)M_ * TWO_D;      // M*D    = 1,048,576
    float* delta    = x + (size_t)M_ * D_;         // M*D
    float* Bm       = delta + (size_t)M_ * D_;     // M*N    =   524,288
    float* Cm       = Bm + (size_t)M_ * N_;        // M*N
    float* y        = Cm + (size_t)M_ * N_;        // M*D
    float* ch_aprod = y + (size_t)M_ * D_;         // B*D*NC*N = 524,288
    float* ch_h     = ch_aprod + (size_t)B_ * D_ * NC * N_;
    float* hin      = ch_h + (size_t)B_ * D_ * NC * N_;

    // 1. up-projection GEMM
    gemm_up_kernel<<<dim3(TWO_D / 64, M_ / 64), 256, 0, stream>>>(
        up_x, W_up, b_up, u, M_, TWO_D, R_);

    // 2. causal conv + silu
    conv_silu_kernel<<<(M_ * D_ + 255) / 256, 256, 0, stream>>>(
        u, conv_w, conv_b, x);

    // 3. delta/B/C projections
    proj_kernel<<<M_, 256, 0, stream>>>(
        x, W_delta, b_delta, W_B, b_B, W_C, b_C, delta, Bm, Cm);

    // 4. chunked selective scan (3 passes)
    scan_chunk_kernel<<<(B_ * D_ * NC) / 4, 256, 0, stream>>>(
        delta, x, Bm, Cm, A_log, D_skip, y, ch_aprod, ch_h);
    scan_prefix_kernel<<<(B_ * D_ * N_ + 255) / 256, 256, 0, stream>>>(
        ch_aprod, ch_h, hin);
    scan_fix_kernel<<<(B_ * D_ * (NC - 1)) / 4 + 1, 256, 0, stream>>>(
        delta, Cm, A_log, hin, y);

    // 5. gate + down-projection GEMM
    gemm_down_kernel<<<dim3(R_ / 64, M_ / 64), 256, 0, stream>>>(
        y, u, W_down, b_down, out, M_, R_, D_);
}

// Round 3
// 370.653 us; speedup vs baseline: 3.5209x; 1.3271x over previous
//
#include <hip/hip_runtime.h>
#include <math.h>

// Problem constants (from reference)
#define B_ 4
#define L_ 2048
#define R_ 1024
#define D_ 128      // ssm input dim
#define N_ 64       // state size
#define TWO_D 256   // 2*D
#define M_ (B_*L_)  // 8192 rows
#define TC 128      // scan chunk length
#define NC (L_/TC)  // 16 chunks per sequence

#define LSTR 40     // LDS row stride in shorts (80 B, 16B-aligned, conflict-light)

typedef __attribute__((ext_vector_type(8))) short bf16x8;
typedef __attribute__((ext_vector_type(4))) float f32x4;

__device__ __forceinline__ float silu_f(float z) {
    return z / (1.0f + __expf(-z));
}

__device__ __forceinline__ float softplus_f(float z) {
    return fmaxf(z, 0.0f) + log1pf(__expf(-fabsf(z)));
}

__device__ __forceinline__ short f2bf(float f) {
    union { float f; unsigned int u; } v; v.f = f;
    unsigned int r = v.u + 0x7FFF + ((v.u >> 16) & 1);   // round-nearest-even
    return (short)(r >> 16);
}

// ---------------------------------------------------------------------------
// Kernel 1: u = up_x @ W_up + b_up   [8192,1024] @ [1024,256] -> [8192,256]
// bf16 MFMA, 64x64 tile, BK=32, cvt fused into staging.
// ---------------------------------------------------------------------------
__global__ __launch_bounds__(256) void gemm_up_mfma(
    const float* __restrict__ A,     // [M,1024]
    const float* __restrict__ W,     // [1024,256]
    const float* __restrict__ bias,  // [256]
    float* __restrict__ C)           // [M,256]
{
    __shared__ short Al[64 * LSTR];
    __shared__ short Bl[64 * LSTR];

    int tid = threadIdx.x;
    int bn = blockIdx.x, bm = blockIdx.y;
    int w = tid >> 6, l = tid & 63;
    int lm = l & 15, q = l >> 4;
    int wm = (w & 1) * 32, wn = (w >> 1) * 32;

    f32x4 acc00 = {0,0,0,0}, acc01 = {0,0,0,0}, acc10 = {0,0,0,0}, acc11 = {0,0,0,0};

    // staging roles
    int ar = tid >> 2, ak = (tid & 3) * 8;     // A: row 0..63, k-offset 0/8/16/24
    int bcol = tid & 63, bk = (tid >> 6) * 8;  // B: col 0..63, k-offset 0/8/16/24

    const float* Ag = A + (size_t)(bm * 64 + ar) * 1024 + ak;
    const float* Wg = W + (size_t)bn * 64 + bcol;

    for (int kt = 0; kt < 1024; kt += 32) {
        // ---- stage A (fp32 -> bf16) ----
        float4 a0 = *(const float4*)(Ag + kt);
        float4 a1 = *(const float4*)(Ag + kt + 4);
        bf16x8 ap;
        ap[0] = f2bf(a0.x); ap[1] = f2bf(a0.y); ap[2] = f2bf(a0.z); ap[3] = f2bf(a0.w);
        ap[4] = f2bf(a1.x); ap[5] = f2bf(a1.y); ap[6] = f2bf(a1.z); ap[7] = f2bf(a1.w);
        *(bf16x8*)&Al[ar * LSTR + ak] = ap;

        // ---- stage B transposed: Bl[n][k] = W[kt+k][bn*64+n] ----
        bf16x8 bp;
        #pragma unroll
        for (int j = 0; j < 8; j++)
            bp[j] = f2bf(Wg[(size_t)(kt + bk + j) * TWO_D]);
        *(bf16x8*)&Bl[bcol * LSTR + bk] = bp;

        __syncthreads();

        bf16x8 af0 = *(bf16x8*)&Al[(wm + lm) * LSTR + q * 8];
        bf16x8 af1 = *(bf16x8*)&Al[(wm + 16 + lm) * LSTR + q * 8];
        bf16x8 bf0 = *(bf16x8*)&Bl[(wn + lm) * LSTR + q * 8];
        bf16x8 bf1 = *(bf16x8*)&Bl[(wn + 16 + lm) * LSTR + q * 8];

        acc00 = __builtin_amdgcn_mfma_f32_16x16x32_bf16(af0, bf0, acc00, 0, 0, 0);
        acc01 = __builtin_amdgcn_mfma_f32_16x16x32_bf16(af0, bf1, acc01, 0, 0, 0);
        acc10 = __builtin_amdgcn_mfma_f32_16x16x32_bf16(af1, bf0, acc10, 0, 0, 0);
        acc11 = __builtin_amdgcn_mfma_f32_16x16x32_bf16(af1, bf1, acc11, 0, 0, 0);

        __syncthreads();
    }

    // epilogue: C/D layout col = lane&15, row = q*4 + i
    #pragma unroll
    for (int i = 0; i < 4; i++) {
        int r0 = bm * 64 + wm + q * 4 + i;
        int r1 = r0 + 16;
        int c0 = bn * 64 + wn + lm;
        int c1 = c0 + 16;
        C[(size_t)r0 * TWO_D + c0] = acc00[i] + bias[c0];
        C[(size_t)r0 * TWO_D + c1] = acc01[i] + bias[c1];
        C[(size_t)r1 * TWO_D + c0] = acc10[i] + bias[c0];
        C[(size_t)r1 * TWO_D + c1] = acc11[i] + bias[c1];
    }
}

// ---------------------------------------------------------------------------
// Kernel 2: causal depthwise conv K=3 + SiLU
// ---------------------------------------------------------------------------
__global__ __launch_bounds__(256) void conv_silu_kernel(
    const float* __restrict__ u,
    const float* __restrict__ conv_w,
    const float* __restrict__ conv_b,
    float* __restrict__ x)
{
    int idx = blockIdx.x * 256 + threadIdx.x;
    if (idx >= M_ * D_) return;
    int r = idx >> 7;
    int c = idx & 127;
    int t = r & (L_ - 1);

    float w0 = conv_w[c * 3 + 0];
    float w1 = conv_w[c * 3 + 1];
    float w2 = conv_w[c * 3 + 2];

    float v2 = u[(size_t)r * TWO_D + c];
    float v1 = (t >= 1) ? u[(size_t)(r - 1) * TWO_D + c] : 0.0f;
    float v0 = (t >= 2) ? u[(size_t)(r - 2) * TWO_D + c] : 0.0f;

    float z = fmaf(w0, v0, fmaf(w1, v1, fmaf(w2, v2, conv_b[c])));
    x[idx] = silu_f(z);
}

// ---------------------------------------------------------------------------
// Kernel 3: delta/B/C projections (wave-specialized per output)
// ---------------------------------------------------------------------------
__global__ __launch_bounds__(256) void proj_kernel(
    const float* __restrict__ x,
    const float* __restrict__ W_delta, const float* __restrict__ b_delta,
    const float* __restrict__ W_B,     const float* __restrict__ b_B,
    const float* __restrict__ W_C,     const float* __restrict__ b_C,
    float* __restrict__ delta,
    float* __restrict__ Bm,
    float* __restrict__ Cm)
{
    __shared__ float xs[128];
    int r = blockIdx.x;
    int tid = threadIdx.x;
    if (tid < 128) xs[tid] = x[(size_t)r * D_ + tid];
    __syncthreads();

    if (tid < 128) {
        int j = tid;
        float acc = b_delta[j];
        #pragma unroll 8
        for (int k = 0; k < 128; k++)
            acc = fmaf(xs[k], W_delta[k * 128 + j], acc);
        delta[(size_t)r * D_ + j] = softplus_f(acc);
    } else if (tid < 192) {
        int n = tid - 128;
        float acc = b_B[n];
        #pragma unroll 8
        for (int k = 0; k < 128; k++)
            acc = fmaf(xs[k], W_B[k * 64 + n], acc);
        Bm[(size_t)r * N_ + n] = acc;
    } else {
        int n = tid - 192;
        float acc = b_C[n];
        #pragma unroll 8
        for (int k = 0; k < 128; k++)
            acc = fmaf(xs[k], W_C[k * 64 + n], acc);
        Cm[(size_t)r * N_ + n] = acc;
    }
}

// ---------------------------------------------------------------------------
// Kernel 4a: chunked scan, pass A — local scan per (b,d,chunk), h_in = 0.
// ---------------------------------------------------------------------------
__global__ __launch_bounds__(256) void scan_chunk_kernel(
    const float* __restrict__ delta,   // [M,D]
    const float* __restrict__ x,       // [M,D]
    const float* __restrict__ Bm,      // [M,N]
    const float* __restrict__ Cm,      // [M,N]
    const float* __restrict__ A_log,   // [D,N]
    const float* __restrict__ D_skip,  // [D]
    float* __restrict__ y,             // [M,D]
    float* __restrict__ ch_aprod,      // [B,D,NC,N]
    float* __restrict__ ch_h)          // [B,D,NC,N]
{
    int w = blockIdx.x * 4 + (threadIdx.x >> 6);
    int n = threadIdx.x & 63;
    int c = w & (NC - 1);
    int d = (w >> 4) & 127;
    int b = w >> 11;

    float A_dn = -__expf(A_log[d * N_ + n]);
    float dsk = D_skip[d];

    size_t row0 = (size_t)b * L_ + c * TC;
    const float* dp = delta + row0 * D_ + d;
    const float* xp = x     + row0 * D_ + d;
    const float* bp = Bm    + row0 * N_ + n;
    const float* cp = Cm    + row0 * N_ + n;
    float*       yp = y     + row0 * D_ + d;

    float h = 0.0f;
    float ap = 1.0f;
    #pragma unroll 4
    for (int t = 0; t < TC; t++) {
        float dl = dp[t * D_];
        float xv = xp[t * D_];
        float bv = bp[t * N_];
        float cv = cp[t * N_];
        float dA = __expf(dl * A_dn);
        h = fmaf(dA, h, dl * bv * xv);
        ap *= dA;
        float p = h * cv;
        #pragma unroll
        for (int off = 32; off >= 1; off >>= 1)
            p += __shfl_xor(p, off, 64);
        if (n == 0) yp[t * D_] = fmaf(dsk, xv, p);
    }

    size_t ci = (((size_t)b * D_ + d) * NC + c) * N_ + n;
    ch_aprod[ci] = ap;
    ch_h[ci] = h;
}

// ---------------------------------------------------------------------------
// Kernel 4b: serial prefix over the 16 chunk summaries, per (b,d,n).
// ---------------------------------------------------------------------------
__global__ __launch_bounds__(256) void scan_prefix_kernel(
    const float* __restrict__ ch_aprod,
    const float* __restrict__ ch_h,
    float* __restrict__ hin)
{
    int idx = blockIdx.x * 256 + threadIdx.x;
    if (idx >= B_ * D_ * N_) return;
    int n = idx & 63;
    int d = (idx >> 6) & 127;
    int b = idx >> 13;

    size_t base = (((size_t)b * D_ + d) * NC) * N_ + n;
    float h = 0.0f;
    #pragma unroll
    for (int c = 0; c < NC; c++) {
        hin[base + (size_t)c * N_] = h;
        h = fmaf(ch_aprod[base + (size_t)c * N_], h, ch_h[base + (size_t)c * N_]);
    }
}

// ---------------------------------------------------------------------------
// Kernel 4c: correction pass — add sum_n (prod dA) * h_in[n] * C_t[n]
// ---------------------------------------------------------------------------
__global__ __launch_bounds__(256) void scan_fix_kernel(
    const float* __restrict__ delta,
    const float* __restrict__ Cm,
    const float* __restrict__ A_log,
    const float* __restrict__ hin,
    float* __restrict__ y)
{
    int w = blockIdx.x * 4 + (threadIdx.x >> 6);
    int n = threadIdx.x & 63;
    int c = (w % (NC - 1)) + 1;
    int rest = w / (NC - 1);
    int d = rest & 127;
    int b = rest >> 7;

    float A_dn = -__expf(A_log[d * N_ + n]);
    float hv = hin[(((size_t)b * D_ + d) * NC + c) * N_ + n];

    size_t row0 = (size_t)b * L_ + c * TC;
    const float* dp = delta + row0 * D_ + d;
    const float* cp = Cm    + row0 * N_ + n;
    float*       yp = y     + row0 * D_ + d;

    float ap = 1.0f;
    #pragma unroll 4
    for (int t = 0; t < TC; t++) {
        float dl = dp[t * D_];
        float cv = cp[t * N_];
        float dA = __expf(dl * A_dn);
        ap *= dA;
        float p = ap * hv * cv;
        #pragma unroll
        for (int off = 32; off >= 1; off >>= 1)
            p += __shfl_xor(p, off, 64);
        if (n == 0) yp[t * D_] += p;
    }
}

// ---------------------------------------------------------------------------
// Kernel 5: out = (y * silu(u_right)) @ W_down + b_down
// bf16 MFMA, gating+cvt fused into A staging. [8192,128]@[128,1024].
// ---------------------------------------------------------------------------
__global__ __launch_bounds__(256) void gemm_down_mfma(
    const float* __restrict__ y,     // [M,128]
    const float* __restrict__ u,     // [M,256] right half gates
    const float* __restrict__ W,     // [128,1024]
    const float* __restrict__ bias,  // [1024]
    float* __restrict__ out)         // [M,1024]
{
    __shared__ short Al[64 * LSTR];
    __shared__ short Bl[64 * LSTR];

    int tid = threadIdx.x;
    int bn = blockIdx.x, bm = blockIdx.y;
    int w = tid >> 6, l = tid & 63;
    int lm = l & 15, q = l >> 4;
    int wm = (w & 1) * 32, wn = (w >> 1) * 32;

    f32x4 acc00 = {0,0,0,0}, acc01 = {0,0,0,0}, acc10 = {0,0,0,0}, acc11 = {0,0,0,0};

    int ar = tid >> 2, ak = (tid & 3) * 8;
    int bcol = tid & 63, bk = (tid >> 6) * 8;

    const float* Yg = y + (size_t)(bm * 64 + ar) * D_ + ak;
    const float* Ug = u + (size_t)(bm * 64 + ar) * TWO_D + D_ + ak;
    const float* Wg = W + (size_t)bn * 64 + bcol;

    for (int kt = 0; kt < 128; kt += 32) {
        float4 y0 = *(const float4*)(Yg + kt);
        float4 y1 = *(const float4*)(Yg + kt + 4);
        float4 g0 = *(const float4*)(Ug + kt);
        float4 g1 = *(const float4*)(Ug + kt + 4);
        bf16x8 ap;
        ap[0] = f2bf(y0.x * silu_f(g0.x)); ap[1] = f2bf(y0.y * silu_f(g0.y));
        ap[2] = f2bf(y0.z * silu_f(g0.z)); ap[3] = f2bf(y0.w * silu_f(g0.w));
        ap[4] = f2bf(y1.x * silu_f(g1.x)); ap[5] = f2bf(y1.y * silu_f(g1.y));
        ap[6] = f2bf(y1.z * silu_f(g1.z)); ap[7] = f2bf(y1.w * silu_f(g1.w));
        *(bf16x8*)&Al[ar * LSTR + ak] = ap;

        bf16x8 bp;
        #pragma unroll
        for (int j = 0; j < 8; j++)
            bp[j] = f2bf(Wg[(size_t)(kt + bk + j) * R_]);
        *(bf16x8*)&Bl[bcol * LSTR + bk] = bp;

        __syncthreads();

        bf16x8 af0 = *(bf16x8*)&Al[(wm + lm) * LSTR + q * 8];
        bf16x8 af1 = *(bf16x8*)&Al[(wm + 16 + lm) * LSTR + q * 8];
        bf16x8 bf0 = *(bf16x8*)&Bl[(wn + lm) * LSTR + q * 8];
        bf16x8 bf1 = *(bf16x8*)&Bl[(wn + 16 + lm) * LSTR + q * 8];

        acc00 = __builtin_amdgcn_mfma_f32_16x16x32_bf16(af0, bf0, acc00, 0, 0, 0);
        acc01 = __builtin_amdgcn_mfma_f32_16x16x32_bf16(af0, bf1, acc01, 0, 0, 0);
        acc10 = __builtin_amdgcn_mfma_f32_16x16x32_bf16(af1, bf0, acc10, 0, 0, 0);
        acc11 = __builtin_amdgcn_mfma_f32_16x16x32_bf16(af1, bf1, acc11, 0, 0, 0);

        __syncthreads();
    }

    #pragma unroll
    for (int i = 0; i < 4; i++) {
        int r0 = bm * 64 + wm + q * 4 + i;
        int r1 = r0 + 16;
        int c0 = bn * 64 + wn + lm;
        int c1 = c0 + 16;
        out[(size_t)r0 * R_ + c0] = acc00[i] + bias[c0];
        out[(size_t)r0 * R_ + c1] = acc01[i] + bias[c1];
        out[(size_t)r1 * R_ + c0] = acc10[i] + bias[c0];
        out[(size_t)r1 * R_ + c1] = acc11[i] + bias[c1];
    }
}

// ---------------------------------------------------------------------------
extern "C" void kernel_launch(void* const* d_in, const int* in_sizes, int n_in,
                              void* d_out, int out_size, void* d_ws, size_t ws_size,
                              hipStream_t stream)
{
    const float* up_x    = (const float*)d_in[0];
    const float* W_up    = (const float*)d_in[1];
    const float* b_up    = (const float*)d_in[2];
    const float* conv_w  = (const float*)d_in[3];
    const float* conv_b  = (const float*)d_in[4];
    const float* W_delta = (const float*)d_in[5];
    const float* b_delta = (const float*)d_in[6];
    const float* W_B     = (const float*)d_in[7];
    const float* b_B     = (const float*)d_in[8];
    const float* W_C     = (const float*)d_in[9];
    const float* b_C     = (const float*)d_in[10];
    const float* A_log   = (const float*)d_in[11];
    const float* D_skip  = (const float*)d_in[12];
    const float* W_down  = (const float*)d_in[13];
    const float* b_down  = (const float*)d_in[14];

    float* out = (float*)d_out;
    float* ws  = (float*)d_ws;

    // workspace layout (floats)
    float* u        = ws;                          // M*2D
    float* x        = u + (size_t)M_ * TWO_D;      // M*D
    float* delta    = x + (size_t)M_ * D_;         // M*D
    float* Bm       = delta + (size_t)M_ * D_;     // M*N
    float* Cm       = Bm + (size_t)M_ * N_;        // M*N
    float* y        = Cm + (size_t)M_ * N_;        // M*D
    float* ch_aprod = y + (size_t)M_ * D_;         // B*D*NC*N
    float* ch_h     = ch_aprod + (size_t)B_ * D_ * NC * N_;
    float* hin      = ch_h + (size_t)B_ * D_ * NC * N_;

    // 1. up-projection GEMM (bf16 MFMA)
    gemm_up_mfma<<<dim3(TWO_D / 64, M_ / 64), 256, 0, stream>>>(
        up_x, W_up, b_up, u);

    // 2. causal conv + silu
    conv_silu_kernel<<<(M_ * D_ + 255) / 256, 256, 0, stream>>>(
        u, conv_w, conv_b, x);

    // 3. delta/B/C projections
    proj_kernel<<<M_, 256, 0, stream>>>(
        x, W_delta, b_delta, W_B, b_B, W_C, b_C, delta, Bm, Cm);

    // 4. chunked selective scan (3 passes)
    scan_chunk_kernel<<<(B_ * D_ * NC) / 4, 256, 0, stream>>>(
        delta, x, Bm, Cm, A_log, D_skip, y, ch_aprod, ch_h);
    scan_prefix_kernel<<<(B_ * D_ * N_ + 255) / 256, 256, 0, stream>>>(
        ch_aprod, ch_h, hin);
    scan_fix_kernel<<<(B_ * D_ * (NC - 1)) / 4 + 1, 256, 0, stream>>>(
        delta, Cm, A_log, hin, y);

    // 5. gate + down-projection GEMM (bf16 MFMA)
    gemm_down_mfma<<<dim3(R_ / 64, M_ / 64), 256, 0, stream>>>(
        y, u, W_down, b_down, out);
}

// Round 4
// 288.464 us; speedup vs baseline: 4.5240x; 1.2849x over previous
//
#include <hip/hip_runtime.h>
#include <math.h>

// Problem constants (from reference)
#define B_ 4
#define L_ 2048
#define R_ 1024
#define D_ 128      // ssm input dim
#define N_ 64       // state size
#define TWO_D 256   // 2*D
#define M_ (B_*L_)  // 8192 rows
#define TC 64       // scan chunk length
#define NC (L_/TC)  // 32 chunks per sequence

#define LSTR 40     // LDS row stride in shorts (80 B, 16B-aligned, conflict-light)

typedef __attribute__((ext_vector_type(8))) short bf16x8;
typedef __attribute__((ext_vector_type(4))) float f32x4;

__device__ __forceinline__ float silu_f(float z) {
    return z / (1.0f + __expf(-z));
}

__device__ __forceinline__ float softplus_f(float z) {
    return fmaxf(z, 0.0f) + log1pf(__expf(-fabsf(z)));
}

__device__ __forceinline__ short f2bf(float f) {
    union { float f; unsigned int u; } v; v.f = f;
    unsigned int r = v.u + 0x7FFF + ((v.u >> 16) & 1);   // round-nearest-even
    return (short)(r >> 16);
}

// ---------------------------------------------------------------------------
// Kernel 1: u = up_x @ W_up + b_up   [8192,1024] @ [1024,256] -> [8192,256]
// bf16 MFMA, 64x64 tile, BK=32, cvt fused into staging.
// ---------------------------------------------------------------------------
__global__ __launch_bounds__(256) void gemm_up_mfma(
    const float* __restrict__ A,     // [M,1024]
    const float* __restrict__ W,     // [1024,256]
    const float* __restrict__ bias,  // [256]
    float* __restrict__ C)           // [M,256]
{
    __shared__ short Al[64 * LSTR];
    __shared__ short Bl[64 * LSTR];

    int tid = threadIdx.x;
    int bn = blockIdx.x, bm = blockIdx.y;
    int w = tid >> 6, l = tid & 63;
    int lm = l & 15, q = l >> 4;
    int wm = (w & 1) * 32, wn = (w >> 1) * 32;

    f32x4 acc00 = {0,0,0,0}, acc01 = {0,0,0,0}, acc10 = {0,0,0,0}, acc11 = {0,0,0,0};

    int ar = tid >> 2, ak = (tid & 3) * 8;
    int bcol = tid & 63, bk = (tid >> 6) * 8;

    const float* Ag = A + (size_t)(bm * 64 + ar) * 1024 + ak;
    const float* Wg = W + (size_t)bn * 64 + bcol;

    for (int kt = 0; kt < 1024; kt += 32) {
        float4 a0 = *(const float4*)(Ag + kt);
        float4 a1 = *(const float4*)(Ag + kt + 4);
        bf16x8 ap;
        ap[0] = f2bf(a0.x); ap[1] = f2bf(a0.y); ap[2] = f2bf(a0.z); ap[3] = f2bf(a0.w);
        ap[4] = f2bf(a1.x); ap[5] = f2bf(a1.y); ap[6] = f2bf(a1.z); ap[7] = f2bf(a1.w);
        *(bf16x8*)&Al[ar * LSTR + ak] = ap;

        bf16x8 bp;
        #pragma unroll
        for (int j = 0; j < 8; j++)
            bp[j] = f2bf(Wg[(size_t)(kt + bk + j) * TWO_D]);
        *(bf16x8*)&Bl[bcol * LSTR + bk] = bp;

        __syncthreads();

        bf16x8 af0 = *(bf16x8*)&Al[(wm + lm) * LSTR + q * 8];
        bf16x8 af1 = *(bf16x8*)&Al[(wm + 16 + lm) * LSTR + q * 8];
        bf16x8 bf0 = *(bf16x8*)&Bl[(wn + lm) * LSTR + q * 8];
        bf16x8 bf1 = *(bf16x8*)&Bl[(wn + 16 + lm) * LSTR + q * 8];

        acc00 = __builtin_amdgcn_mfma_f32_16x16x32_bf16(af0, bf0, acc00, 0, 0, 0);
        acc01 = __builtin_amdgcn_mfma_f32_16x16x32_bf16(af0, bf1, acc01, 0, 0, 0);
        acc10 = __builtin_amdgcn_mfma_f32_16x16x32_bf16(af1, bf0, acc10, 0, 0, 0);
        acc11 = __builtin_amdgcn_mfma_f32_16x16x32_bf16(af1, bf1, acc11, 0, 0, 0);

        __syncthreads();
    }

    #pragma unroll
    for (int i = 0; i < 4; i++) {
        int r0 = bm * 64 + wm + q * 4 + i;
        int r1 = r0 + 16;
        int c0 = bn * 64 + wn + lm;
        int c1 = c0 + 16;
        C[(size_t)r0 * TWO_D + c0] = acc00[i] + bias[c0];
        C[(size_t)r0 * TWO_D + c1] = acc01[i] + bias[c1];
        C[(size_t)r1 * TWO_D + c0] = acc10[i] + bias[c0];
        C[(size_t)r1 * TWO_D + c1] = acc11[i] + bias[c1];
    }
}

// ---------------------------------------------------------------------------
// Kernel 2: causal depthwise conv K=3 + SiLU
// ---------------------------------------------------------------------------
__global__ __launch_bounds__(256) void conv_silu_kernel(
    const float* __restrict__ u,
    const float* __restrict__ conv_w,
    const float* __restrict__ conv_b,
    float* __restrict__ x)
{
    int idx = blockIdx.x * 256 + threadIdx.x;
    if (idx >= M_ * D_) return;
    int r = idx >> 7;
    int c = idx & 127;
    int t = r & (L_ - 1);

    float w0 = conv_w[c * 3 + 0];
    float w1 = conv_w[c * 3 + 1];
    float w2 = conv_w[c * 3 + 2];

    float v2 = u[(size_t)r * TWO_D + c];
    float v1 = (t >= 1) ? u[(size_t)(r - 1) * TWO_D + c] : 0.0f;
    float v0 = (t >= 2) ? u[(size_t)(r - 2) * TWO_D + c] : 0.0f;

    float z = fmaf(w0, v0, fmaf(w1, v1, fmaf(w2, v2, conv_b[c])));
    x[idx] = silu_f(z);
}

// ---------------------------------------------------------------------------
// Kernel 3: delta/B/C projections (wave-specialized per output)
// ---------------------------------------------------------------------------
__global__ __launch_bounds__(256) void proj_kernel(
    const float* __restrict__ x,
    const float* __restrict__ W_delta, const float* __restrict__ b_delta,
    const float* __restrict__ W_B,     const float* __restrict__ b_B,
    const float* __restrict__ W_C,     const float* __restrict__ b_C,
    float* __restrict__ delta,
    float* __restrict__ Bm,
    float* __restrict__ Cm)
{
    __shared__ float xs[128];
    int r = blockIdx.x;
    int tid = threadIdx.x;
    if (tid < 128) xs[tid] = x[(size_t)r * D_ + tid];
    __syncthreads();

    if (tid < 128) {
        int j = tid;
        float acc = b_delta[j];
        #pragma unroll 8
        for (int k = 0; k < 128; k++)
            acc = fmaf(xs[k], W_delta[k * 128 + j], acc);
        delta[(size_t)r * D_ + j] = softplus_f(acc);
    } else if (tid < 192) {
        int n = tid - 128;
        float acc = b_B[n];
        #pragma unroll 8
        for (int k = 0; k < 128; k++)
            acc = fmaf(xs[k], W_B[k * 64 + n], acc);
        Bm[(size_t)r * N_ + n] = acc;
    } else {
        int n = tid - 192;
        float acc = b_C[n];
        #pragma unroll 8
        for (int k = 0; k < 128; k++)
            acc = fmaf(xs[k], W_C[k * 64 + n], acc);
        Cm[(size_t)r * N_ + n] = acc;
    }
}

// ---------------------------------------------------------------------------
// Kernel 4a: chunked scan pass A — 4 d-channels per wave, 4 states per lane.
// lane = g*16+j: channel d_base+g, states n=4j..4j+3. Butterfly over 16 lanes.
// y may alias x (each y[t,d] store value depends on the x[t,d] load).
// ---------------------------------------------------------------------------
__global__ __launch_bounds__(256) void scan_chunk4_kernel(
    const float* __restrict__ delta,   // [M,D]
    const float* xin,                  // [M,D]  (may alias yout)
    const float* __restrict__ Bm,      // [M,N]
    const float* __restrict__ Cm,      // [M,N]
    const float* __restrict__ A_log,   // [D,N]
    const float* __restrict__ D_skip,  // [D]
    float* yout,                       // [M,D]  (may alias xin)
    float* __restrict__ ch_aprod,      // [B,D,NC,N]
    float* __restrict__ ch_h)          // [B,D,NC,N]
{
    int wid = blockIdx.x * 4 + (threadIdx.x >> 6);  // 0..B*(D/4)*NC-1 = 4095
    int l = threadIdx.x & 63;
    int g = l >> 4, j = l & 15;
    int c = wid & (NC - 1);          // NC=32
    int dq = (wid >> 5) & 31;        // D/4=32
    int b = wid >> 10;
    int d = dq * 4 + g;

    const float LOG2E = 1.44269504089f;
    float4 Ar = *(const float4*)&A_log[d * N_ + j * 4];
    float Ai0 = -__expf(Ar.x) * LOG2E;
    float Ai1 = -__expf(Ar.y) * LOG2E;
    float Ai2 = -__expf(Ar.z) * LOG2E;
    float Ai3 = -__expf(Ar.w) * LOG2E;
    float dsk = D_skip[d];

    size_t row0 = (size_t)b * L_ + c * TC;
    const float* dp = delta + row0 * D_ + d;
    const float* xp = xin   + row0 * D_ + d;
    const float* bp = Bm    + row0 * N_ + j * 4;
    const float* cp = Cm    + row0 * N_ + j * 4;
    float*       yp = yout  + row0 * D_ + d;

    float h0 = 0, h1 = 0, h2 = 0, h3 = 0;
    float a0 = 1, a1 = 1, a2 = 1, a3 = 1;

    #pragma unroll 4
    for (int t = 0; t < TC; t++) {
        float dl = dp[t * D_];
        float xv = xp[t * D_];
        float4 bv = *(const float4*)&bp[t * N_];
        float4 cv = *(const float4*)&cp[t * N_];
        float e0 = exp2f(dl * Ai0);
        float e1 = exp2f(dl * Ai1);
        float e2 = exp2f(dl * Ai2);
        float e3 = exp2f(dl * Ai3);
        float dbx = dl * xv;
        h0 = fmaf(e0, h0, dbx * bv.x); a0 *= e0;
        h1 = fmaf(e1, h1, dbx * bv.y); a1 *= e1;
        h2 = fmaf(e2, h2, dbx * bv.z); a2 *= e2;
        h3 = fmaf(e3, h3, dbx * bv.w); a3 *= e3;
        float p = fmaf(h0, cv.x, fmaf(h1, cv.y, fmaf(h2, cv.z, h3 * cv.w)));
        p += __shfl_xor(p, 1, 64);
        p += __shfl_xor(p, 2, 64);
        p += __shfl_xor(p, 4, 64);
        p += __shfl_xor(p, 8, 64);
        if (j == 0) yp[t * D_] = fmaf(dsk, xv, p);
    }

    size_t ci = (((size_t)b * D_ + d) * NC + c) * N_ + j * 4;
    *(float4*)&ch_aprod[ci] = make_float4(a0, a1, a2, a3);
    *(float4*)&ch_h[ci]     = make_float4(h0, h1, h2, h3);
}

// ---------------------------------------------------------------------------
// Kernel 4b: serial prefix over NC chunk summaries, per (b,d,n).
// hin overwrites ch_aprod in place (read-before-write per element).
// ---------------------------------------------------------------------------
__global__ __launch_bounds__(256) void scan_prefix_kernel(
    float* aprod_hin,                  // in: chunk aprod; out: hin
    const float* __restrict__ ch_h)
{
    int idx = blockIdx.x * 256 + threadIdx.x;   // B*D*N = 32768 exact
    int n = idx & 63;
    int rest = idx >> 6;                         // b*D + d
    size_t base = (size_t)rest * NC * N_ + n;
    float h = 0.0f;
    #pragma unroll
    for (int c = 0; c < NC; c++) {
        size_t o = base + (size_t)c * N_;
        float a  = aprod_hin[o];
        float hh = ch_h[o];
        aprod_hin[o] = h;
        h = fmaf(a, h, hh);
    }
}

// ---------------------------------------------------------------------------
// Kernel 4c: correction — y[t,d] += sum_n (hin[n] * prod_{s<=t} dA_s) * C_t[n]
// Same 4-d / 4-n layout; running product seeded with hin.
// ---------------------------------------------------------------------------
__global__ __launch_bounds__(256) void scan_fix4_kernel(
    const float* __restrict__ delta,
    const float* __restrict__ Cm,
    const float* __restrict__ A_log,
    const float* __restrict__ hin,     // [B,D,NC,N]
    float* __restrict__ y)
{
    int wid = blockIdx.x * 4 + (threadIdx.x >> 6);  // 0..B*(D/4)*(NC-1)-1 = 3967
    int l = threadIdx.x & 63;
    int g = l >> 4, j = l & 15;
    int c = wid % (NC - 1) + 1;
    int rest = wid / (NC - 1);
    int dq = rest & 31;
    int b = rest >> 5;
    int d = dq * 4 + g;

    const float LOG2E = 1.44269504089f;
    float4 Ar = *(const float4*)&A_log[d * N_ + j * 4];
    float Ai0 = -__expf(Ar.x) * LOG2E;
    float Ai1 = -__expf(Ar.y) * LOG2E;
    float Ai2 = -__expf(Ar.z) * LOG2E;
    float Ai3 = -__expf(Ar.w) * LOG2E;

    float4 hv = *(const float4*)&hin[(((size_t)b * D_ + d) * NC + c) * N_ + j * 4];
    float a0 = hv.x, a1 = hv.y, a2 = hv.z, a3 = hv.w;

    size_t row0 = (size_t)b * L_ + c * TC;
    const float* dp = delta + row0 * D_ + d;
    const float* cp = Cm    + row0 * N_ + j * 4;
    float*       yp = y     + row0 * D_ + d;

    #pragma unroll 4
    for (int t = 0; t < TC; t++) {
        float dl = dp[t * D_];
        float4 cv = *(const float4*)&cp[t * N_];
        a0 *= exp2f(dl * Ai0);
        a1 *= exp2f(dl * Ai1);
        a2 *= exp2f(dl * Ai2);
        a3 *= exp2f(dl * Ai3);
        float p = fmaf(a0, cv.x, fmaf(a1, cv.y, fmaf(a2, cv.z, a3 * cv.w)));
        p += __shfl_xor(p, 1, 64);
        p += __shfl_xor(p, 2, 64);
        p += __shfl_xor(p, 4, 64);
        p += __shfl_xor(p, 8, 64);
        if (j == 0) yp[t * D_] += p;
    }
}

// ---------------------------------------------------------------------------
// Kernel 5: out = (y * silu(u_right)) @ W_down + b_down
// bf16 MFMA, gating+cvt fused into A staging. [8192,128]@[128,1024].
// ---------------------------------------------------------------------------
__global__ __launch_bounds__(256) void gemm_down_mfma(
    const float* __restrict__ y,     // [M,128]
    const float* __restrict__ u,     // [M,256] right half gates
    const float* __restrict__ W,     // [128,1024]
    const float* __restrict__ bias,  // [1024]
    float* __restrict__ out)         // [M,1024]
{
    __shared__ short Al[64 * LSTR];
    __shared__ short Bl[64 * LSTR];

    int tid = threadIdx.x;
    int bn = blockIdx.x, bm = blockIdx.y;
    int w = tid >> 6, l = tid & 63;
    int lm = l & 15, q = l >> 4;
    int wm = (w & 1) * 32, wn = (w >> 1) * 32;

    f32x4 acc00 = {0,0,0,0}, acc01 = {0,0,0,0}, acc10 = {0,0,0,0}, acc11 = {0,0,0,0};

    int ar = tid >> 2, ak = (tid & 3) * 8;
    int bcol = tid & 63, bk = (tid >> 6) * 8;

    const float* Yg = y + (size_t)(bm * 64 + ar) * D_ + ak;
    const float* Ug = u + (size_t)(bm * 64 + ar) * TWO_D + D_ + ak;
    const float* Wg = W + (size_t)bn * 64 + bcol;

    for (int kt = 0; kt < 128; kt += 32) {
        float4 y0 = *(const float4*)(Yg + kt);
        float4 y1 = *(const float4*)(Yg + kt + 4);
        float4 g0 = *(const float4*)(Ug + kt);
        float4 g1 = *(const float4*)(Ug + kt + 4);
        bf16x8 ap;
        ap[0] = f2bf(y0.x * silu_f(g0.x)); ap[1] = f2bf(y0.y * silu_f(g0.y));
        ap[2] = f2bf(y0.z * silu_f(g0.z)); ap[3] = f2bf(y0.w * silu_f(g0.w));
        ap[4] = f2bf(y1.x * silu_f(g1.x)); ap[5] = f2bf(y1.y * silu_f(g1.y));
        ap[6] = f2bf(y1.z * silu_f(g1.z)); ap[7] = f2bf(y1.w * silu_f(g1.w));
        *(bf16x8*)&Al[ar * LSTR + ak] = ap;

        bf16x8 bp;
        #pragma unroll
        for (int j = 0; j < 8; j++)
            bp[j] = f2bf(Wg[(size_t)(kt + bk + j) * R_]);
        *(bf16x8*)&Bl[bcol * LSTR + bk] = bp;

        __syncthreads();

        bf16x8 af0 = *(bf16x8*)&Al[(wm + lm) * LSTR + q * 8];
        bf16x8 af1 = *(bf16x8*)&Al[(wm + 16 + lm) * LSTR + q * 8];
        bf16x8 bf0 = *(bf16x8*)&Bl[(wn + lm) * LSTR + q * 8];
        bf16x8 bf1 = *(bf16x8*)&Bl[(wn + 16 + lm) * LSTR + q * 8];

        acc00 = __builtin_amdgcn_mfma_f32_16x16x32_bf16(af0, bf0, acc00, 0, 0, 0);
        acc01 = __builtin_amdgcn_mfma_f32_16x16x32_bf16(af0, bf1, acc01, 0, 0, 0);
        acc10 = __builtin_amdgcn_mfma_f32_16x16x32_bf16(af1, bf0, acc10, 0, 0, 0);
        acc11 = __builtin_amdgcn_mfma_f32_16x16x32_bf16(af1, bf1, acc11, 0, 0, 0);

        __syncthreads();
    }

    #pragma unroll
    for (int i = 0; i < 4; i++) {
        int r0 = bm * 64 + wm + q * 4 + i;
        int r1 = r0 + 16;
        int c0 = bn * 64 + wn + lm;
        int c1 = c0 + 16;
        out[(size_t)r0 * R_ + c0] = acc00[i] + bias[c0];
        out[(size_t)r0 * R_ + c1] = acc01[i] + bias[c1];
        out[(size_t)r1 * R_ + c0] = acc10[i] + bias[c0];
        out[(size_t)r1 * R_ + c1] = acc11[i] + bias[c1];
    }
}

// ---------------------------------------------------------------------------
extern "C" void kernel_launch(void* const* d_in, const int* in_sizes, int n_in,
                              void* d_out, int out_size, void* d_ws, size_t ws_size,
                              hipStream_t stream)
{
    const float* up_x    = (const float*)d_in[0];
    const float* W_up    = (const float*)d_in[1];
    const float* b_up    = (const float*)d_in[2];
    const float* conv_w  = (const float*)d_in[3];
    const float* conv_b  = (const float*)d_in[4];
    const float* W_delta = (const float*)d_in[5];
    const float* b_delta = (const float*)d_in[6];
    const float* W_B     = (const float*)d_in[7];
    const float* b_B     = (const float*)d_in[8];
    const float* W_C     = (const float*)d_in[9];
    const float* b_C     = (const float*)d_in[10];
    const float* A_log   = (const float*)d_in[11];
    const float* D_skip  = (const float*)d_in[12];
    const float* W_down  = (const float*)d_in[13];
    const float* b_down  = (const float*)d_in[14];

    float* out = (float*)d_out;
    float* ws  = (float*)d_ws;

    // workspace layout (floats), 7,340,032 floats = 28 MB total
    float* u        = ws;                          // M*2D = 2,097,152
    float* x        = u + (size_t)M_ * TWO_D;      // M*D  = 1,048,576  (y aliases x)
    float* delta    = x + (size_t)M_ * D_;         // M*D
    float* Bm       = delta + (size_t)M_ * D_;     // M*N  = 524,288
    float* Cm       = Bm + (size_t)M_ * N_;        // M*N
    float* ch_aprod = Cm + (size_t)M_ * N_;        // B*D*NC*N = 1,048,576 (hin aliases)
    float* ch_h     = ch_aprod + (size_t)B_ * D_ * NC * N_;  // 1,048,576
    float* y        = x;          // alias: scan pass A reads x[t,d] then writes y[t,d]
    float* hin      = ch_aprod;   // alias: prefix overwrites aprod in place

    // 1. up-projection GEMM (bf16 MFMA)
    gemm_up_mfma<<<dim3(TWO_D / 64, M_ / 64), 256, 0, stream>>>(
        up_x, W_up, b_up, u);

    // 2. causal conv + silu
    conv_silu_kernel<<<(M_ * D_ + 255) / 256, 256, 0, stream>>>(
        u, conv_w, conv_b, x);

    // 3. delta/B/C projections
    proj_kernel<<<M_, 256, 0, stream>>>(
        x, W_delta, b_delta, W_B, b_B, W_C, b_C, delta, Bm, Cm);

    // 4. chunked selective scan (3 passes), 4 channels/wave, 4 states/lane
    scan_chunk4_kernel<<<(B_ * (D_ / 4) * NC) / 4, 256, 0, stream>>>(
        delta, x, Bm, Cm, A_log, D_skip, y, ch_aprod, ch_h);
    scan_prefix_kernel<<<(B_ * D_ * N_) / 256, 256, 0, stream>>>(
        ch_aprod, ch_h);
    scan_fix4_kernel<<<(B_ * (D_ / 4) * (NC - 1)) / 4, 256, 0, stream>>>(
        delta, Cm, A_log, hin, y);

    // 5. gate + down-projection GEMM (bf16 MFMA)
    gemm_down_mfma<<<dim3(R_ / 64, M_ / 64), 256, 0, stream>>>(
        y, u, W_down, b_down, out);
}

// Round 5
// 256.566 us; speedup vs baseline: 5.0865x; 1.1243x over previous
//
#include <hip/hip_runtime.h>
#include <math.h>

// Problem constants (from reference)
#define B_ 4
#define L_ 2048
#define R_ 1024
#define D_ 128      // ssm input dim
#define N_ 64       // state size
#define TWO_D 256   // 2*D
#define M_ (B_*L_)  // 8192 rows

#define LSTR 40     // LDS row stride in shorts (80 B, 16B-aligned, conflict-light)

typedef __attribute__((ext_vector_type(8))) short bf16x8;
typedef __attribute__((ext_vector_type(4))) float f32x4;

__device__ __forceinline__ float silu_f(float z) {
    return z / (1.0f + __expf(-z));
}

__device__ __forceinline__ float softplus_f(float z) {
    return fmaxf(z, 0.0f) + log1pf(__expf(-fabsf(z)));
}

__device__ __forceinline__ short f2bf(float f) {
    union { float f; unsigned int u; } v; v.f = f;
    unsigned int r = v.u + 0x7FFF + ((v.u >> 16) & 1);   // round-nearest-even
    return (short)(r >> 16);
}

// ---------------------------------------------------------------------------
// Kernel 1: u = up_x @ W_up + b_up   [8192,1024] @ [1024,256] -> [8192,256]
// bf16 MFMA, 64x64 tile, BK=32, cvt fused into staging.
// ---------------------------------------------------------------------------
__global__ __launch_bounds__(256) void gemm_up_mfma(
    const float* __restrict__ A,     // [M,1024]
    const float* __restrict__ W,     // [1024,256]
    const float* __restrict__ bias,  // [256]
    float* __restrict__ C)           // [M,256]
{
    __shared__ short Al[64 * LSTR];
    __shared__ short Bl[64 * LSTR];

    int tid = threadIdx.x;
    int bn = blockIdx.x, bm = blockIdx.y;
    int w = tid >> 6, l = tid & 63;
    int lm = l & 15, q = l >> 4;
    int wm = (w & 1) * 32, wn = (w >> 1) * 32;

    f32x4 acc00 = {0,0,0,0}, acc01 = {0,0,0,0}, acc10 = {0,0,0,0}, acc11 = {0,0,0,0};

    int ar = tid >> 2, ak = (tid & 3) * 8;
    int bcol = tid & 63, bk = (tid >> 6) * 8;

    const float* Ag = A + (size_t)(bm * 64 + ar) * 1024 + ak;
    const float* Wg = W + (size_t)bn * 64 + bcol;

    for (int kt = 0; kt < 1024; kt += 32) {
        float4 a0 = *(const float4*)(Ag + kt);
        float4 a1 = *(const float4*)(Ag + kt + 4);
        bf16x8 ap;
        ap[0] = f2bf(a0.x); ap[1] = f2bf(a0.y); ap[2] = f2bf(a0.z); ap[3] = f2bf(a0.w);
        ap[4] = f2bf(a1.x); ap[5] = f2bf(a1.y); ap[6] = f2bf(a1.z); ap[7] = f2bf(a1.w);
        *(bf16x8*)&Al[ar * LSTR + ak] = ap;

        bf16x8 bp;
        #pragma unroll
        for (int j = 0; j < 8; j++)
            bp[j] = f2bf(Wg[(size_t)(kt + bk + j) * TWO_D]);
        *(bf16x8*)&Bl[bcol * LSTR + bk] = bp;

        __syncthreads();

        bf16x8 af0 = *(bf16x8*)&Al[(wm + lm) * LSTR + q * 8];
        bf16x8 af1 = *(bf16x8*)&Al[(wm + 16 + lm) * LSTR + q * 8];
        bf16x8 bf0 = *(bf16x8*)&Bl[(wn + lm) * LSTR + q * 8];
        bf16x8 bf1 = *(bf16x8*)&Bl[(wn + 16 + lm) * LSTR + q * 8];

        acc00 = __builtin_amdgcn_mfma_f32_16x16x32_bf16(af0, bf0, acc00, 0, 0, 0);
        acc01 = __builtin_amdgcn_mfma_f32_16x16x32_bf16(af0, bf1, acc01, 0, 0, 0);
        acc10 = __builtin_amdgcn_mfma_f32_16x16x32_bf16(af1, bf0, acc10, 0, 0, 0);
        acc11 = __builtin_amdgcn_mfma_f32_16x16x32_bf16(af1, bf1, acc11, 0, 0, 0);

        __syncthreads();
    }

    #pragma unroll
    for (int i = 0; i < 4; i++) {
        int r0 = bm * 64 + wm + q * 4 + i;
        int r1 = r0 + 16;
        int c0 = bn * 64 + wn + lm;
        int c1 = c0 + 16;
        C[(size_t)r0 * TWO_D + c0] = acc00[i] + bias[c0];
        C[(size_t)r0 * TWO_D + c1] = acc01[i] + bias[c1];
        C[(size_t)r1 * TWO_D + c0] = acc10[i] + bias[c0];
        C[(size_t)r1 * TWO_D + c1] = acc11[i] + bias[c1];
    }
}

// ---------------------------------------------------------------------------
// Kernel 2: causal depthwise conv K=3 + SiLU
// ---------------------------------------------------------------------------
__global__ __launch_bounds__(256) void conv_silu_kernel(
    const float* __restrict__ u,
    const float* __restrict__ conv_w,
    const float* __restrict__ conv_b,
    float* __restrict__ x)
{
    int idx = blockIdx.x * 256 + threadIdx.x;
    if (idx >= M_ * D_) return;
    int r = idx >> 7;
    int c = idx & 127;
    int t = r & (L_ - 1);

    float w0 = conv_w[c * 3 + 0];
    float w1 = conv_w[c * 3 + 1];
    float w2 = conv_w[c * 3 + 2];

    float v2 = u[(size_t)r * TWO_D + c];
    float v1 = (t >= 1) ? u[(size_t)(r - 1) * TWO_D + c] : 0.0f;
    float v0 = (t >= 2) ? u[(size_t)(r - 2) * TWO_D + c] : 0.0f;

    float z = fmaf(w0, v0, fmaf(w1, v1, fmaf(w2, v2, conv_b[c])));
    x[idx] = silu_f(z);
}

// ---------------------------------------------------------------------------
// Kernel 3: delta/B/C projections (wave-specialized per output)
// ---------------------------------------------------------------------------
__global__ __launch_bounds__(256) void proj_kernel(
    const float* __restrict__ x,
    const float* __restrict__ W_delta, const float* __restrict__ b_delta,
    const float* __restrict__ W_B,     const float* __restrict__ b_B,
    const float* __restrict__ W_C,     const float* __restrict__ b_C,
    float* __restrict__ delta,
    float* __restrict__ Bm,
    float* __restrict__ Cm)
{
    __shared__ float xs[128];
    int r = blockIdx.x;
    int tid = threadIdx.x;
    if (tid < 128) xs[tid] = x[(size_t)r * D_ + tid];
    __syncthreads();

    if (tid < 128) {
        int j = tid;
        float acc = b_delta[j];
        #pragma unroll 8
        for (int k = 0; k < 128; k++)
            acc = fmaf(xs[k], W_delta[k * 128 + j], acc);
        delta[(size_t)r * D_ + j] = softplus_f(acc);
    } else if (tid < 192) {
        int n = tid - 128;
        float acc = b_B[n];
        #pragma unroll 8
        for (int k = 0; k < 128; k++)
            acc = fmaf(xs[k], W_B[k * 64 + n], acc);
        Bm[(size_t)r * N_ + n] = acc;
    } else {
        int n = tid - 192;
        float acc = b_C[n];
        #pragma unroll 8
        for (int k = 0; k < 128; k++)
            acc = fmaf(xs[k], W_C[k * 64 + n], acc);
        Cm[(size_t)r * N_ + n] = acc;
    }
}

// ---------------------------------------------------------------------------
// Kernel 4a: summary pass — per (b, d-quad, chunk) wave, 4 states per lane.
// lane = g*16+j: channel d=dq*4+g, states n=4j..4j+3.
// No Cm reads, no shuffles, no y stores. Chunk dA-product via exp2(Ai*sum(dl)).
// ---------------------------------------------------------------------------
template<int LOG_NC>
__global__ __launch_bounds__(256) void scan_sumA(
    const float* __restrict__ delta,   // [M,D]
    const float* __restrict__ x,       // [M,D]
    const float* __restrict__ Bm,      // [M,N]
    const float* __restrict__ A_log,   // [D,N]
    float* __restrict__ ch_aprod,      // [B,D,NC,N]
    float* __restrict__ ch_h)          // [B,D,NC,N]
{
    constexpr int NCt = 1 << LOG_NC;
    constexpr int TCt = L_ >> LOG_NC;

    int wid = blockIdx.x * 4 + (threadIdx.x >> 6);
    int l = threadIdx.x & 63;
    int g = l >> 4, j = l & 15;
    int c = wid & (NCt - 1);
    int dq = (wid >> LOG_NC) & 31;
    int b = wid >> (LOG_NC + 5);
    int d = dq * 4 + g;

    const float LOG2E = 1.44269504089f;
    float4 Ar = *(const float4*)&A_log[d * N_ + j * 4];
    float Ai0 = -__expf(Ar.x) * LOG2E;
    float Ai1 = -__expf(Ar.y) * LOG2E;
    float Ai2 = -__expf(Ar.z) * LOG2E;
    float Ai3 = -__expf(Ar.w) * LOG2E;

    size_t row0 = (size_t)b * L_ + c * TCt;
    const float* dp = delta + row0 * D_ + d;
    const float* xp = x     + row0 * D_ + d;
    const float* bp = Bm    + row0 * N_ + j * 4;

    float h0 = 0, h1 = 0, h2 = 0, h3 = 0;
    float S = 0;

    #pragma unroll 8
    for (int t = 0; t < TCt; t++) {
        float dl = dp[t * D_];
        float xv = xp[t * D_];
        float4 bv = *(const float4*)&bp[t * N_];
        float e0 = exp2f(dl * Ai0);
        float e1 = exp2f(dl * Ai1);
        float e2 = exp2f(dl * Ai2);
        float e3 = exp2f(dl * Ai3);
        float dbx = dl * xv;
        h0 = fmaf(e0, h0, dbx * bv.x);
        h1 = fmaf(e1, h1, dbx * bv.y);
        h2 = fmaf(e2, h2, dbx * bv.z);
        h3 = fmaf(e3, h3, dbx * bv.w);
        S += dl;
    }

    size_t ci = (((size_t)b * D_ + d) * NCt + c) * N_ + j * 4;
    *(float4*)&ch_aprod[ci] = make_float4(exp2f(Ai0 * S), exp2f(Ai1 * S),
                                          exp2f(Ai2 * S), exp2f(Ai3 * S));
    *(float4*)&ch_h[ci]     = make_float4(h0, h1, h2, h3);
}

// ---------------------------------------------------------------------------
// Kernel 4b: serial prefix over NC chunk summaries, per (b,d,n).
// hin overwrites ch_aprod in place (read-before-write per element).
// ---------------------------------------------------------------------------
template<int LOG_NC>
__global__ __launch_bounds__(256) void scan_prefix(
    float* __restrict__ aprod_hin,     // in: chunk aprod; out: hin
    const float* __restrict__ ch_h)
{
    constexpr int NCt = 1 << LOG_NC;
    int idx = blockIdx.x * 256 + threadIdx.x;   // B*D*N = 32768 exact
    int n = idx & 63;
    int rest = idx >> 6;                         // b*D + d
    size_t base = (size_t)rest * NCt * N_ + n;
    float h = 0.0f;
    #pragma unroll 8
    for (int c = 0; c < NCt; c++) {
        size_t o = base + (size_t)c * N_;
        float a  = aprod_hin[o];
        float hh = ch_h[o];
        aprod_hin[o] = h;
        h = fmaf(a, h, hh);
    }
}

// ---------------------------------------------------------------------------
// Kernel 4c: output pass — all chunks, h seeded from hin (zero for chunk 0).
// Full recurrence + dot(C) + 4-step butterfly over 16 lanes + y store.
// ---------------------------------------------------------------------------
template<int LOG_NC>
__global__ __launch_bounds__(256) void scan_outB(
    const float* __restrict__ delta,   // [M,D]
    const float* __restrict__ x,       // [M,D]
    const float* __restrict__ Bm,      // [M,N]
    const float* __restrict__ Cm,      // [M,N]
    const float* __restrict__ A_log,   // [D,N]
    const float* __restrict__ D_skip,  // [D]
    const float* __restrict__ hin,     // [B,D,NC,N]
    float* __restrict__ y)             // [M,D]
{
    constexpr int NCt = 1 << LOG_NC;
    constexpr int TCt = L_ >> LOG_NC;

    int wid = blockIdx.x * 4 + (threadIdx.x >> 6);
    int l = threadIdx.x & 63;
    int g = l >> 4, j = l & 15;
    int c = wid & (NCt - 1);
    int dq = (wid >> LOG_NC) & 31;
    int b = wid >> (LOG_NC + 5);
    int d = dq * 4 + g;

    const float LOG2E = 1.44269504089f;
    float4 Ar = *(const float4*)&A_log[d * N_ + j * 4];
    float Ai0 = -__expf(Ar.x) * LOG2E;
    float Ai1 = -__expf(Ar.y) * LOG2E;
    float Ai2 = -__expf(Ar.z) * LOG2E;
    float Ai3 = -__expf(Ar.w) * LOG2E;
    float dsk = D_skip[d];

    float4 hv = *(const float4*)&hin[(((size_t)b * D_ + d) * NCt + c) * N_ + j * 4];
    float h0 = hv.x, h1 = hv.y, h2 = hv.z, h3 = hv.w;

    size_t row0 = (size_t)b * L_ + c * TCt;
    const float* dp = delta + row0 * D_ + d;
    const float* xp = x     + row0 * D_ + d;
    const float* bp = Bm    + row0 * N_ + j * 4;
    const float* cp = Cm    + row0 * N_ + j * 4;
    float*       yp = y     + row0 * D_ + d;

    #pragma unroll 8
    for (int t = 0; t < TCt; t++) {
        float dl = dp[t * D_];
        float xv = xp[t * D_];
        float4 bv = *(const float4*)&bp[t * N_];
        float4 cv = *(const float4*)&cp[t * N_];
        float e0 = exp2f(dl * Ai0);
        float e1 = exp2f(dl * Ai1);
        float e2 = exp2f(dl * Ai2);
        float e3 = exp2f(dl * Ai3);
        float dbx = dl * xv;
        h0 = fmaf(e0, h0, dbx * bv.x);
        h1 = fmaf(e1, h1, dbx * bv.y);
        h2 = fmaf(e2, h2, dbx * bv.z);
        h3 = fmaf(e3, h3, dbx * bv.w);
        float p = fmaf(h0, cv.x, fmaf(h1, cv.y, fmaf(h2, cv.z, h3 * cv.w)));
        p += __shfl_xor(p, 1, 64);
        p += __shfl_xor(p, 2, 64);
        p += __shfl_xor(p, 4, 64);
        p += __shfl_xor(p, 8, 64);
        if (j == 0) yp[t * D_] = fmaf(dsk, xv, p);
    }
}

// ---------------------------------------------------------------------------
// Kernel 5: out = (y * silu(u_right)) @ W_down + b_down
// bf16 MFMA, gating+cvt fused into A staging. [8192,128]@[128,1024].
// ---------------------------------------------------------------------------
__global__ __launch_bounds__(256) void gemm_down_mfma(
    const float* __restrict__ y,     // [M,128]
    const float* __restrict__ u,     // [M,256] right half gates
    const float* __restrict__ W,     // [128,1024]
    const float* __restrict__ bias,  // [1024]
    float* __restrict__ out)         // [M,1024]
{
    __shared__ short Al[64 * LSTR];
    __shared__ short Bl[64 * LSTR];

    int tid = threadIdx.x;
    int bn = blockIdx.x, bm = blockIdx.y;
    int w = tid >> 6, l = tid & 63;
    int lm = l & 15, q = l >> 4;
    int wm = (w & 1) * 32, wn = (w >> 1) * 32;

    f32x4 acc00 = {0,0,0,0}, acc01 = {0,0,0,0}, acc10 = {0,0,0,0}, acc11 = {0,0,0,0};

    int ar = tid >> 2, ak = (tid & 3) * 8;
    int bcol = tid & 63, bk = (tid >> 6) * 8;

    const float* Yg = y + (size_t)(bm * 64 + ar) * D_ + ak;
    const float* Ug = u + (size_t)(bm * 64 + ar) * TWO_D + D_ + ak;
    const float* Wg = W + (size_t)bn * 64 + bcol;

    for (int kt = 0; kt < 128; kt += 32) {
        float4 y0 = *(const float4*)(Yg + kt);
        float4 y1 = *(const float4*)(Yg + kt + 4);
        float4 g0 = *(const float4*)(Ug + kt);
        float4 g1 = *(const float4*)(Ug + kt + 4);
        bf16x8 ap;
        ap[0] = f2bf(y0.x * silu_f(g0.x)); ap[1] = f2bf(y0.y * silu_f(g0.y));
        ap[2] = f2bf(y0.z * silu_f(g0.z)); ap[3] = f2bf(y0.w * silu_f(g0.w));
        ap[4] = f2bf(y1.x * silu_f(g1.x)); ap[5] = f2bf(y1.y * silu_f(g1.y));
        ap[6] = f2bf(y1.z * silu_f(g1.z)); ap[7] = f2bf(y1.w * silu_f(g1.w));
        *(bf16x8*)&Al[ar * LSTR + ak] = ap;

        bf16x8 bp;
        #pragma unroll
        for (int j = 0; j < 8; j++)
            bp[j] = f2bf(Wg[(size_t)(kt + bk + j) * R_]);
        *(bf16x8*)&Bl[bcol * LSTR + bk] = bp;

        __syncthreads();

        bf16x8 af0 = *(bf16x8*)&Al[(wm + lm) * LSTR + q * 8];
        bf16x8 af1 = *(bf16x8*)&Al[(wm + 16 + lm) * LSTR + q * 8];
        bf16x8 bf0 = *(bf16x8*)&Bl[(wn + lm) * LSTR + q * 8];
        bf16x8 bf1 = *(bf16x8*)&Bl[(wn + 16 + lm) * LSTR + q * 8];

        acc00 = __builtin_amdgcn_mfma_f32_16x16x32_bf16(af0, bf0, acc00, 0, 0, 0);
        acc01 = __builtin_amdgcn_mfma_f32_16x16x32_bf16(af0, bf1, acc01, 0, 0, 0);
        acc10 = __builtin_amdgcn_mfma_f32_16x16x32_bf16(af1, bf0, acc10, 0, 0, 0);
        acc11 = __builtin_amdgcn_mfma_f32_16x16x32_bf16(af1, bf1, acc11, 0, 0, 0);

        __syncthreads();
    }

    #pragma unroll
    for (int i = 0; i < 4; i++) {
        int r0 = bm * 64 + wm + q * 4 + i;
        int r1 = r0 + 16;
        int c0 = bn * 64 + wn + lm;
        int c1 = c0 + 16;
        out[(size_t)r0 * R_ + c0] = acc00[i] + bias[c0];
        out[(size_t)r0 * R_ + c1] = acc01[i] + bias[c1];
        out[(size_t)r1 * R_ + c0] = acc10[i] + bias[c0];
        out[(size_t)r1 * R_ + c1] = acc11[i] + bias[c1];
    }
}

// ---------------------------------------------------------------------------
extern "C" void kernel_launch(void* const* d_in, const int* in_sizes, int n_in,
                              void* d_out, int out_size, void* d_ws, size_t ws_size,
                              hipStream_t stream)
{
    const float* up_x    = (const float*)d_in[0];
    const float* W_up    = (const float*)d_in[1];
    const float* b_up    = (const float*)d_in[2];
    const float* conv_w  = (const float*)d_in[3];
    const float* conv_b  = (const float*)d_in[4];
    const float* W_delta = (const float*)d_in[5];
    const float* b_delta = (const float*)d_in[6];
    const float* W_B     = (const float*)d_in[7];
    const float* b_B     = (const float*)d_in[8];
    const float* W_C     = (const float*)d_in[9];
    const float* b_C     = (const float*)d_in[10];
    const float* A_log   = (const float*)d_in[11];
    const float* D_skip  = (const float*)d_in[12];
    const float* W_down  = (const float*)d_in[13];
    const float* b_down  = (const float*)d_in[14];

    float* out = (float*)d_out;
    float* ws  = (float*)d_ws;

    // fixed part of workspace (floats): u, x, delta, Bm, Cm, y
    float* u     = ws;                          // M*2D = 2,097,152
    float* x     = u + (size_t)M_ * TWO_D;      // M*D  = 1,048,576
    float* delta = x + (size_t)M_ * D_;         // M*D
    float* Bm    = delta + (size_t)M_ * D_;     // M*N  = 524,288
    float* Cm    = Bm + (size_t)M_ * N_;        // M*N
    float* y     = Cm + (size_t)M_ * N_;        // M*D
    float* ch_aprod = y + (size_t)M_ * D_;      // B*D*NC*N (NC-dependent)
    // layout totals: NC=64 -> 41,943,040 B; NC=32 -> 33,554,432 B
    bool big = ws_size >= (size_t)41943040;

    // 1. up-projection GEMM (bf16 MFMA)
    gemm_up_mfma<<<dim3(TWO_D / 64, M_ / 64), 256, 0, stream>>>(
        up_x, W_up, b_up, u);

    // 2. causal conv + silu
    conv_silu_kernel<<<(M_ * D_ + 255) / 256, 256, 0, stream>>>(
        u, conv_w, conv_b, x);

    // 3. delta/B/C projections
    proj_kernel<<<M_, 256, 0, stream>>>(
        x, W_delta, b_delta, W_B, b_B, W_C, b_C, delta, Bm, Cm);

    // 4. chunked selective scan: summaries -> prefix -> output
    if (big) {
        constexpr int LNC = 6;                       // NC=64, TC=32
        float* ch_h = ch_aprod + (size_t)B_ * D_ * (1 << LNC) * N_;
        scan_sumA<LNC><<<(B_ * (D_ / 4) * (1 << LNC)) / 4, 256, 0, stream>>>(
            delta, x, Bm, A_log, ch_aprod, ch_h);
        scan_prefix<LNC><<<(B_ * D_ * N_) / 256, 256, 0, stream>>>(
            ch_aprod, ch_h);
        scan_outB<LNC><<<(B_ * (D_ / 4) * (1 << LNC)) / 4, 256, 0, stream>>>(
            delta, x, Bm, Cm, A_log, D_skip, ch_aprod, y);
    } else {
        constexpr int LNC = 5;                       // NC=32, TC=64
        float* ch_h = ch_aprod + (size_t)B_ * D_ * (1 << LNC) * N_;
        scan_sumA<LNC><<<(B_ * (D_ / 4) * (1 << LNC)) / 4, 256, 0, stream>>>(
            delta, x, Bm, A_log, ch_aprod, ch_h);
        scan_prefix<LNC><<<(B_ * D_ * N_) / 256, 256, 0, stream>>>(
            ch_aprod, ch_h);
        scan_outB<LNC><<<(B_ * (D_ / 4) * (1 << LNC)) / 4, 256, 0, stream>>>(
            delta, x, Bm, Cm, A_log, D_skip, ch_aprod, y);
    }

    // 5. gate + down-projection GEMM (bf16 MFMA)
    gemm_down_mfma<<<dim3(R_ / 64, M_ / 64), 256, 0, stream>>>(
        y, u, W_down, b_down, out);
}

// Round 6
// 223.910 us; speedup vs baseline: 5.8283x; 1.1458x over previous
//
#include <hip/hip_runtime.h>
#include <math.h>

// Problem constants (from reference)
#define B_ 4
#define L_ 2048
#define R_ 1024
#define D_ 128      // ssm input dim
#define N_ 64       // state size
#define TWO_D 256   // 2*D
#define M_ (B_*L_)  // 8192 rows

// LDS row stride in shorts: 68 shorts = 136 B = 34 dwords; 34 mod 32 = 2 ->
// max 2-way bank aliasing on staging writes / frag reads (free on CDNA4).
#define LSTR 68

typedef __attribute__((ext_vector_type(8))) short bf16x8;
typedef __attribute__((ext_vector_type(4))) float f32x4;

__device__ __forceinline__ float silu_f(float z) {
    return z / (1.0f + __expf(-z));
}

__device__ __forceinline__ float softplus_f(float z) {
    return fmaxf(z, 0.0f) + log1pf(__expf(-fabsf(z)));
}

__device__ __forceinline__ short f2bf(float f) {
    union { float f; unsigned int u; } v; v.f = f;
    unsigned int r = v.u + 0x7FFF + ((v.u >> 16) & 1);   // round-nearest-even
    return (short)(r >> 16);
}

// ---------------------------------------------------------------------------
// Kernel 1: u = up_x @ W_up + b_up   [8192,1024] @ [1024,256] -> [8192,256]
// bf16 MFMA, 64x64 tile, BK=32. Flat grid + XCD swizzle: each XCD owns a
// contiguous 16-bm stripe and all 4 bn -> A streamed through its L2 once.
// ---------------------------------------------------------------------------
__global__ __launch_bounds__(256) void gemm_up_mfma(
    const float* __restrict__ A,     // [M,1024]
    const float* __restrict__ W,     // [1024,256]
    const float* __restrict__ bias,  // [256]
    float* __restrict__ C)           // [M,256]
{
    __shared__ short Al[64 * LSTR];
    __shared__ short Bl[64 * LSTR];

    int lid = blockIdx.x;            // 0..511
    int xcd = lid & 7;
    int slot = lid >> 3;             // 0..63
    int bm = xcd * 16 + (slot >> 2); // 0..127
    int bn = slot & 3;               // 0..3

    int tid = threadIdx.x;
    int w = tid >> 6, l = tid & 63;
    int lm = l & 15, q = l >> 4;
    int wm = (w & 1) * 32, wn = (w >> 1) * 32;

    f32x4 acc00 = {0,0,0,0}, acc01 = {0,0,0,0}, acc10 = {0,0,0,0}, acc11 = {0,0,0,0};

    int ar = tid >> 2, ak = (tid & 3) * 8;
    int bcol = tid & 63, bk = (tid >> 6) * 8;

    const float* Ag = A + (size_t)(bm * 64 + ar) * 1024 + ak;
    const float* Wg = W + (size_t)bn * 64 + bcol;

    for (int kt = 0; kt < 1024; kt += 32) {
        float4 a0 = *(const float4*)(Ag + kt);
        float4 a1 = *(const float4*)(Ag + kt + 4);
        bf16x8 ap;
        ap[0] = f2bf(a0.x); ap[1] = f2bf(a0.y); ap[2] = f2bf(a0.z); ap[3] = f2bf(a0.w);
        ap[4] = f2bf(a1.x); ap[5] = f2bf(a1.y); ap[6] = f2bf(a1.z); ap[7] = f2bf(a1.w);
        *(bf16x8*)&Al[ar * LSTR + ak] = ap;

        bf16x8 bp;
        #pragma unroll
        for (int j = 0; j < 8; j++)
            bp[j] = f2bf(Wg[(size_t)(kt + bk + j) * TWO_D]);
        *(bf16x8*)&Bl[bcol * LSTR + bk] = bp;

        __syncthreads();

        bf16x8 af0 = *(bf16x8*)&Al[(wm + lm) * LSTR + q * 8];
        bf16x8 af1 = *(bf16x8*)&Al[(wm + 16 + lm) * LSTR + q * 8];
        bf16x8 bf0 = *(bf16x8*)&Bl[(wn + lm) * LSTR + q * 8];
        bf16x8 bf1 = *(bf16x8*)&Bl[(wn + 16 + lm) * LSTR + q * 8];

        acc00 = __builtin_amdgcn_mfma_f32_16x16x32_bf16(af0, bf0, acc00, 0, 0, 0);
        acc01 = __builtin_amdgcn_mfma_f32_16x16x32_bf16(af0, bf1, acc01, 0, 0, 0);
        acc10 = __builtin_amdgcn_mfma_f32_16x16x32_bf16(af1, bf0, acc10, 0, 0, 0);
        acc11 = __builtin_amdgcn_mfma_f32_16x16x32_bf16(af1, bf1, acc11, 0, 0, 0);

        __syncthreads();
    }

    #pragma unroll
    for (int i = 0; i < 4; i++) {
        int r0 = bm * 64 + wm + q * 4 + i;
        int r1 = r0 + 16;
        int c0 = bn * 64 + wn + lm;
        int c1 = c0 + 16;
        C[(size_t)r0 * TWO_D + c0] = acc00[i] + bias[c0];
        C[(size_t)r0 * TWO_D + c1] = acc01[i] + bias[c1];
        C[(size_t)r1 * TWO_D + c0] = acc10[i] + bias[c0];
        C[(size_t)r1 * TWO_D + c1] = acc11[i] + bias[c1];
    }
}

// ---------------------------------------------------------------------------
// Kernel 2: causal depthwise conv K=3 + SiLU
// ---------------------------------------------------------------------------
__global__ __launch_bounds__(256) void conv_silu_kernel(
    const float* __restrict__ u,
    const float* __restrict__ conv_w,
    const float* __restrict__ conv_b,
    float* __restrict__ x)
{
    int idx = blockIdx.x * 256 + threadIdx.x;
    if (idx >= M_ * D_) return;
    int r = idx >> 7;
    int c = idx & 127;
    int t = r & (L_ - 1);

    float w0 = conv_w[c * 3 + 0];
    float w1 = conv_w[c * 3 + 1];
    float w2 = conv_w[c * 3 + 2];

    float v2 = u[(size_t)r * TWO_D + c];
    float v1 = (t >= 1) ? u[(size_t)(r - 1) * TWO_D + c] : 0.0f;
    float v0 = (t >= 2) ? u[(size_t)(r - 2) * TWO_D + c] : 0.0f;

    float z = fmaf(w0, v0, fmaf(w1, v1, fmaf(w2, v2, conv_b[c])));
    x[idx] = silu_f(z);
}

// ---------------------------------------------------------------------------
// Kernel 3: fused delta/B/C projection as one bf16 MFMA GEMM:
// x[8192,128] @ [W_delta | W_B | W_C][128,256] -> [8192,256]
// bn selects the weight matrix (block-uniform). Epilogue: softplus for the
// delta columns (bn 0,1); plain writes for Bm (bn 2) / Cm (bn 3).
// ---------------------------------------------------------------------------
__global__ __launch_bounds__(256) void proj_mfma(
    const float* __restrict__ x,       // [M,128]
    const float* __restrict__ W_delta, const float* __restrict__ b_delta,
    const float* __restrict__ W_B,     const float* __restrict__ b_B,
    const float* __restrict__ W_C,     const float* __restrict__ b_C,
    float* __restrict__ delta,         // [M,128]
    float* __restrict__ Bm,            // [M,64]
    float* __restrict__ Cm)            // [M,64]
{
    __shared__ short Al[64 * LSTR];
    __shared__ short Bl[64 * LSTR];

    int lid = blockIdx.x;            // 0..511
    int xcd = lid & 7;
    int slot = lid >> 3;
    int bm = xcd * 16 + (slot >> 2);
    int bn = slot & 3;

    // block-uniform weight/bias select
    const float* Wsel; const float* bsel; int wstride;
    if (bn < 2)       { Wsel = W_delta + bn * 64; bsel = b_delta + bn * 64; wstride = 128; }
    else if (bn == 2) { Wsel = W_B;               bsel = b_B;               wstride = 64;  }
    else              { Wsel = W_C;               bsel = b_C;               wstride = 64;  }

    int tid = threadIdx.x;
    int w = tid >> 6, l = tid & 63;
    int lm = l & 15, q = l >> 4;
    int wm = (w & 1) * 32, wn = (w >> 1) * 32;

    f32x4 acc00 = {0,0,0,0}, acc01 = {0,0,0,0}, acc10 = {0,0,0,0}, acc11 = {0,0,0,0};

    int ar = tid >> 2, ak = (tid & 3) * 8;
    int bcol = tid & 63, bk = (tid >> 6) * 8;

    const float* Ag = x + (size_t)(bm * 64 + ar) * D_ + ak;
    const float* Wg = Wsel + bcol;

    for (int kt = 0; kt < 128; kt += 32) {
        float4 a0 = *(const float4*)(Ag + kt);
        float4 a1 = *(const float4*)(Ag + kt + 4);
        bf16x8 ap;
        ap[0] = f2bf(a0.x); ap[1] = f2bf(a0.y); ap[2] = f2bf(a0.z); ap[3] = f2bf(a0.w);
        ap[4] = f2bf(a1.x); ap[5] = f2bf(a1.y); ap[6] = f2bf(a1.z); ap[7] = f2bf(a1.w);
        *(bf16x8*)&Al[ar * LSTR + ak] = ap;

        bf16x8 bp;
        #pragma unroll
        for (int j = 0; j < 8; j++)
            bp[j] = f2bf(Wg[(size_t)(kt + bk + j) * wstride]);
        *(bf16x8*)&Bl[bcol * LSTR + bk] = bp;

        __syncthreads();

        bf16x8 af0 = *(bf16x8*)&Al[(wm + lm) * LSTR + q * 8];
        bf16x8 af1 = *(bf16x8*)&Al[(wm + 16 + lm) * LSTR + q * 8];
        bf16x8 bf0 = *(bf16x8*)&Bl[(wn + lm) * LSTR + q * 8];
        bf16x8 bf1 = *(bf16x8*)&Bl[(wn + 16 + lm) * LSTR + q * 8];

        acc00 = __builtin_amdgcn_mfma_f32_16x16x32_bf16(af0, bf0, acc00, 0, 0, 0);
        acc01 = __builtin_amdgcn_mfma_f32_16x16x32_bf16(af0, bf1, acc01, 0, 0, 0);
        acc10 = __builtin_amdgcn_mfma_f32_16x16x32_bf16(af1, bf0, acc10, 0, 0, 0);
        acc11 = __builtin_amdgcn_mfma_f32_16x16x32_bf16(af1, bf1, acc11, 0, 0, 0);

        __syncthreads();
    }

    #pragma unroll
    for (int i = 0; i < 4; i++) {
        int r0 = bm * 64 + wm + q * 4 + i;
        int r1 = r0 + 16;
        int c0 = wn + lm;            // 0..63 within this bn tile
        int c1 = c0 + 16;
        float v00 = acc00[i] + bsel[c0];
        float v01 = acc01[i] + bsel[c1];
        float v10 = acc10[i] + bsel[c0];
        float v11 = acc11[i] + bsel[c1];
        if (bn < 2) {
            int cc0 = bn * 64 + c0, cc1 = bn * 64 + c1;
            delta[(size_t)r0 * D_ + cc0] = softplus_f(v00);
            delta[(size_t)r0 * D_ + cc1] = softplus_f(v01);
            delta[(size_t)r1 * D_ + cc0] = softplus_f(v10);
            delta[(size_t)r1 * D_ + cc1] = softplus_f(v11);
        } else if (bn == 2) {
            Bm[(size_t)r0 * N_ + c0] = v00;
            Bm[(size_t)r0 * N_ + c1] = v01;
            Bm[(size_t)r1 * N_ + c0] = v10;
            Bm[(size_t)r1 * N_ + c1] = v11;
        } else {
            Cm[(size_t)r0 * N_ + c0] = v00;
            Cm[(size_t)r0 * N_ + c1] = v01;
            Cm[(size_t)r1 * N_ + c0] = v10;
            Cm[(size_t)r1 * N_ + c1] = v11;
        }
    }
}

// ---------------------------------------------------------------------------
// Kernel 4a: summary pass — per (b, d-quad, chunk) wave, 4 states per lane.
// ---------------------------------------------------------------------------
template<int LOG_NC>
__global__ __launch_bounds__(256) void scan_sumA(
    const float* __restrict__ delta,   // [M,D]
    const float* __restrict__ x,       // [M,D]
    const float* __restrict__ Bm,      // [M,N]
    const float* __restrict__ A_log,   // [D,N]
    float* __restrict__ ch_aprod,      // [B,D,NC,N]
    float* __restrict__ ch_h)          // [B,D,NC,N]
{
    constexpr int NCt = 1 << LOG_NC;
    constexpr int TCt = L_ >> LOG_NC;

    int wid = blockIdx.x * 4 + (threadIdx.x >> 6);
    int l = threadIdx.x & 63;
    int g = l >> 4, j = l & 15;
    int c = wid & (NCt - 1);
    int dq = (wid >> LOG_NC) & 31;
    int b = wid >> (LOG_NC + 5);
    int d = dq * 4 + g;

    const float LOG2E = 1.44269504089f;
    float4 Ar = *(const float4*)&A_log[d * N_ + j * 4];
    float Ai0 = -__expf(Ar.x) * LOG2E;
    float Ai1 = -__expf(Ar.y) * LOG2E;
    float Ai2 = -__expf(Ar.z) * LOG2E;
    float Ai3 = -__expf(Ar.w) * LOG2E;

    size_t row0 = (size_t)b * L_ + c * TCt;
    const float* dp = delta + row0 * D_ + d;
    const float* xp = x     + row0 * D_ + d;
    const float* bp = Bm    + row0 * N_ + j * 4;

    float h0 = 0, h1 = 0, h2 = 0, h3 = 0;
    float S = 0;

    #pragma unroll 8
    for (int t = 0; t < TCt; t++) {
        float dl = dp[t * D_];
        float xv = xp[t * D_];
        float4 bv = *(const float4*)&bp[t * N_];
        float e0 = exp2f(dl * Ai0);
        float e1 = exp2f(dl * Ai1);
        float e2 = exp2f(dl * Ai2);
        float e3 = exp2f(dl * Ai3);
        float dbx = dl * xv;
        h0 = fmaf(e0, h0, dbx * bv.x);
        h1 = fmaf(e1, h1, dbx * bv.y);
        h2 = fmaf(e2, h2, dbx * bv.z);
        h3 = fmaf(e3, h3, dbx * bv.w);
        S += dl;
    }

    size_t ci = (((size_t)b * D_ + d) * NCt + c) * N_ + j * 4;
    *(float4*)&ch_aprod[ci] = make_float4(exp2f(Ai0 * S), exp2f(Ai1 * S),
                                          exp2f(Ai2 * S), exp2f(Ai3 * S));
    *(float4*)&ch_h[ci]     = make_float4(h0, h1, h2, h3);
}

// ---------------------------------------------------------------------------
// Kernel 4b: serial prefix over NC chunk summaries, per (b,d,n).
// ---------------------------------------------------------------------------
template<int LOG_NC>
__global__ __launch_bounds__(256) void scan_prefix(
    float* __restrict__ aprod_hin,     // in: chunk aprod; out: hin
    const float* __restrict__ ch_h)
{
    constexpr int NCt = 1 << LOG_NC;
    int idx = blockIdx.x * 256 + threadIdx.x;   // B*D*N = 32768 exact
    int n = idx & 63;
    int rest = idx >> 6;                         // b*D + d
    size_t base = (size_t)rest * NCt * N_ + n;
    float h = 0.0f;
    #pragma unroll 8
    for (int c = 0; c < NCt; c++) {
        size_t o = base + (size_t)c * N_;
        float a  = aprod_hin[o];
        float hh = ch_h[o];
        aprod_hin[o] = h;
        h = fmaf(a, h, hh);
    }
}

// ---------------------------------------------------------------------------
// Kernel 4c: output pass — all chunks, h seeded from hin (zero for chunk 0).
// ---------------------------------------------------------------------------
template<int LOG_NC>
__global__ __launch_bounds__(256) void scan_outB(
    const float* __restrict__ delta,   // [M,D]
    const float* __restrict__ x,       // [M,D]
    const float* __restrict__ Bm,      // [M,N]
    const float* __restrict__ Cm,      // [M,N]
    const float* __restrict__ A_log,   // [D,N]
    const float* __restrict__ D_skip,  // [D]
    const float* __restrict__ hin,     // [B,D,NC,N]
    float* __restrict__ y)             // [M,D]
{
    constexpr int NCt = 1 << LOG_NC;
    constexpr int TCt = L_ >> LOG_NC;

    int wid = blockIdx.x * 4 + (threadIdx.x >> 6);
    int l = threadIdx.x & 63;
    int g = l >> 4, j = l & 15;
    int c = wid & (NCt - 1);
    int dq = (wid >> LOG_NC) & 31;
    int b = wid >> (LOG_NC + 5);
    int d = dq * 4 + g;

    const float LOG2E = 1.44269504089f;
    float4 Ar = *(const float4*)&A_log[d * N_ + j * 4];
    float Ai0 = -__expf(Ar.x) * LOG2E;
    float Ai1 = -__expf(Ar.y) * LOG2E;
    float Ai2 = -__expf(Ar.z) * LOG2E;
    float Ai3 = -__expf(Ar.w) * LOG2E;
    float dsk = D_skip[d];

    float4 hv = *(const float4*)&hin[(((size_t)b * D_ + d) * NCt + c) * N_ + j * 4];
    float h0 = hv.x, h1 = hv.y, h2 = hv.z, h3 = hv.w;

    size_t row0 = (size_t)b * L_ + c * TCt;
    const float* dp = delta + row0 * D_ + d;
    const float* xp = x     + row0 * D_ + d;
    const float* bp = Bm    + row0 * N_ + j * 4;
    const float* cp = Cm    + row0 * N_ + j * 4;
    float*       yp = y     + row0 * D_ + d;

    #pragma unroll 8
    for (int t = 0; t < TCt; t++) {
        float dl = dp[t * D_];
        float xv = xp[t * D_];
        float4 bv = *(const float4*)&bp[t * N_];
        float4 cv = *(const float4*)&cp[t * N_];
        float e0 = exp2f(dl * Ai0);
        float e1 = exp2f(dl * Ai1);
        float e2 = exp2f(dl * Ai2);
        float e3 = exp2f(dl * Ai3);
        float dbx = dl * xv;
        h0 = fmaf(e0, h0, dbx * bv.x);
        h1 = fmaf(e1, h1, dbx * bv.y);
        h2 = fmaf(e2, h2, dbx * bv.z);
        h3 = fmaf(e3, h3, dbx * bv.w);
        float p = fmaf(h0, cv.x, fmaf(h1, cv.y, fmaf(h2, cv.z, h3 * cv.w)));
        p += __shfl_xor(p, 1, 64);
        p += __shfl_xor(p, 2, 64);
        p += __shfl_xor(p, 4, 64);
        p += __shfl_xor(p, 8, 64);
        if (j == 0) yp[t * D_] = fmaf(dsk, xv, p);
    }
}

// ---------------------------------------------------------------------------
// Kernel 5: out = (y * silu(u_right)) @ W_down + b_down
// bf16 MFMA, gating+cvt fused into A staging. [8192,128]@[128,1024].
// XCD swizzle: 2048 blocks = 8 XCD x (16 bm x 16 bn).
// ---------------------------------------------------------------------------
__global__ __launch_bounds__(256) void gemm_down_mfma(
    const float* __restrict__ y,     // [M,128]
    const float* __restrict__ u,     // [M,256] right half gates
    const float* __restrict__ W,     // [128,1024]
    const float* __restrict__ bias,  // [1024]
    float* __restrict__ out)         // [M,1024]
{
    __shared__ short Al[64 * LSTR];
    __shared__ short Bl[64 * LSTR];

    int lid = blockIdx.x;            // 0..2047
    int xcd = lid & 7;
    int slot = lid >> 3;             // 0..255
    int bm = xcd * 16 + (slot >> 4); // 0..127
    int bn = slot & 15;              // 0..15

    int tid = threadIdx.x;
    int w = tid >> 6, l = tid & 63;
    int lm = l & 15, q = l >> 4;
    int wm = (w & 1) * 32, wn = (w >> 1) * 32;

    f32x4 acc00 = {0,0,0,0}, acc01 = {0,0,0,0}, acc10 = {0,0,0,0}, acc11 = {0,0,0,0};

    int ar = tid >> 2, ak = (tid & 3) * 8;
    int bcol = tid & 63, bk = (tid >> 6) * 8;

    const float* Yg = y + (size_t)(bm * 64 + ar) * D_ + ak;
    const float* Ug = u + (size_t)(bm * 64 + ar) * TWO_D + D_ + ak;
    const float* Wg = W + (size_t)bn * 64 + bcol;

    for (int kt = 0; kt < 128; kt += 32) {
        float4 y0 = *(const float4*)(Yg + kt);
        float4 y1 = *(const float4*)(Yg + kt + 4);
        float4 g0 = *(const float4*)(Ug + kt);
        float4 g1 = *(const float4*)(Ug + kt + 4);
        bf16x8 ap;
        ap[0] = f2bf(y0.x * silu_f(g0.x)); ap[1] = f2bf(y0.y * silu_f(g0.y));
        ap[2] = f2bf(y0.z * silu_f(g0.z)); ap[3] = f2bf(y0.w * silu_f(g0.w));
        ap[4] = f2bf(y1.x * silu_f(g1.x)); ap[5] = f2bf(y1.y * silu_f(g1.y));
        ap[6] = f2bf(y1.z * silu_f(g1.z)); ap[7] = f2bf(y1.w * silu_f(g1.w));
        *(bf16x8*)&Al[ar * LSTR + ak] = ap;

        bf16x8 bp;
        #pragma unroll
        for (int j = 0; j < 8; j++)
            bp[j] = f2bf(Wg[(size_t)(kt + bk + j) * R_]);
        *(bf16x8*)&Bl[bcol * LSTR + bk] = bp;

        __syncthreads();

        bf16x8 af0 = *(bf16x8*)&Al[(wm + lm) * LSTR + q * 8];
        bf16x8 af1 = *(bf16x8*)&Al[(wm + 16 + lm) * LSTR + q * 8];
        bf16x8 bf0 = *(bf16x8*)&Bl[(wn + lm) * LSTR + q * 8];
        bf16x8 bf1 = *(bf16x8*)&Bl[(wn + 16 + lm) * LSTR + q * 8];

        acc00 = __builtin_amdgcn_mfma_f32_16x16x32_bf16(af0, bf0, acc00, 0, 0, 0);
        acc01 = __builtin_amdgcn_mfma_f32_16x16x32_bf16(af0, bf1, acc01, 0, 0, 0);
        acc10 = __builtin_amdgcn_mfma_f32_16x16x32_bf16(af1, bf0, acc10, 0, 0, 0);
        acc11 = __builtin_amdgcn_mfma_f32_16x16x32_bf16(af1, bf1, acc11, 0, 0, 0);

        __syncthreads();
    }

    #pragma unroll
    for (int i = 0; i < 4; i++) {
        int r0 = bm * 64 + wm + q * 4 + i;
        int r1 = r0 + 16;
        int c0 = bn * 64 + wn + lm;
        int c1 = c0 + 16;
        out[(size_t)r0 * R_ + c0] = acc00[i] + bias[c0];
        out[(size_t)r0 * R_ + c1] = acc01[i] + bias[c1];
        out[(size_t)r1 * R_ + c0] = acc10[i] + bias[c0];
        out[(size_t)r1 * R_ + c1] = acc11[i] + bias[c1];
    }
}

// ---------------------------------------------------------------------------
extern "C" void kernel_launch(void* const* d_in, const int* in_sizes, int n_in,
                              void* d_out, int out_size, void* d_ws, size_t ws_size,
                              hipStream_t stream)
{
    const float* up_x    = (const float*)d_in[0];
    const float* W_up    = (const float*)d_in[1];
    const float* b_up    = (const float*)d_in[2];
    const float* conv_w  = (const float*)d_in[3];
    const float* conv_b  = (const float*)d_in[4];
    const float* W_delta = (const float*)d_in[5];
    const float* b_delta = (const float*)d_in[6];
    const float* W_B     = (const float*)d_in[7];
    const float* b_B     = (const float*)d_in[8];
    const float* W_C     = (const float*)d_in[9];
    const float* b_C     = (const float*)d_in[10];
    const float* A_log   = (const float*)d_in[11];
    const float* D_skip  = (const float*)d_in[12];
    const float* W_down  = (const float*)d_in[13];
    const float* b_down  = (const float*)d_in[14];

    float* out = (float*)d_out;
    float* ws  = (float*)d_ws;

    // fixed part of workspace (floats): u, x, delta, Bm, Cm, y
    float* u     = ws;                          // M*2D = 2,097,152
    float* x     = u + (size_t)M_ * TWO_D;      // M*D  = 1,048,576
    float* delta = x + (size_t)M_ * D_;         // M*D
    float* Bm    = delta + (size_t)M_ * D_;     // M*N  = 524,288
    float* Cm    = Bm + (size_t)M_ * N_;        // M*N
    float* y     = Cm + (size_t)M_ * N_;        // M*D
    float* ch_aprod = y + (size_t)M_ * D_;      // B*D*NC*N (NC-dependent)
    // layout totals: NC=64 -> 41,943,040 B; NC=32 -> 33,554,432 B
    bool big = ws_size >= (size_t)41943040;

    // 1. up-projection GEMM (bf16 MFMA, XCD-swizzled)
    gemm_up_mfma<<<(TWO_D / 64) * (M_ / 64), 256, 0, stream>>>(
        up_x, W_up, b_up, u);

    // 2. causal conv + silu
    conv_silu_kernel<<<(M_ * D_ + 255) / 256, 256, 0, stream>>>(
        u, conv_w, conv_b, x);

    // 3. fused delta/B/C projection (bf16 MFMA, XCD-swizzled)
    proj_mfma<<<4 * (M_ / 64), 256, 0, stream>>>(
        x, W_delta, b_delta, W_B, b_B, W_C, b_C, delta, Bm, Cm);

    // 4. chunked selective scan: summaries -> prefix -> output
    if (big) {
        constexpr int LNC = 6;                       // NC=64, TC=32
        float* ch_h = ch_aprod + (size_t)B_ * D_ * (1 << LNC) * N_;
        scan_sumA<LNC><<<(B_ * (D_ / 4) * (1 << LNC)) / 4, 256, 0, stream>>>(
            delta, x, Bm, A_log, ch_aprod, ch_h);
        scan_prefix<LNC><<<(B_ * D_ * N_) / 256, 256, 0, stream>>>(
            ch_aprod, ch_h);
        scan_outB<LNC><<<(B_ * (D_ / 4) * (1 << LNC)) / 4, 256, 0, stream>>>(
            delta, x, Bm, Cm, A_log, D_skip, ch_aprod, y);
    } else {
        constexpr int LNC = 5;                       // NC=32, TC=64
        float* ch_h = ch_aprod + (size_t)B_ * D_ * (1 << LNC) * N_;
        scan_sumA<LNC><<<(B_ * (D_ / 4) * (1 << LNC)) / 4, 256, 0, stream>>>(
            delta, x, Bm, A_log, ch_aprod, ch_h);
        scan_prefix<LNC><<<(B_ * D_ * N_) / 256, 256, 0, stream>>>(
            ch_aprod, ch_h);
        scan_outB<LNC><<<(B_ * (D_ / 4) * (1 << LNC)) / 4, 256, 0, stream>>>(
            delta, x, Bm, Cm, A_log, D_skip, ch_aprod, y);
    }

    // 5. gate + down-projection GEMM (bf16 MFMA, XCD-swizzled)
    gemm_down_mfma<<<16 * (M_ / 64), 256, 0, stream>>>(
        y, u, W_down, b_down, out);
}

// Round 8
// 218.661 us; speedup vs baseline: 5.9682x; 1.0240x over previous
//
#include <hip/hip_runtime.h>
#include <math.h>

// Problem constants (from reference)
#define B_ 4
#define L_ 2048
#define R_ 1024
#define D_ 128      // ssm input dim
#define N_ 64       // state size
#define TWO_D 256   // 2*D
#define M_ (B_*L_)  // 8192 rows

// LDS row stride in shorts: 68 shorts = 136 B = 34 dwords; 34 mod 32 = 2 ->
// max 2-way bank aliasing (free on CDNA4).
#define LSTR 68

typedef __attribute__((ext_vector_type(8))) short bf16x8;
typedef __attribute__((ext_vector_type(4))) float f32x4;

__device__ __forceinline__ float silu_f(float z) {
    return z / (1.0f + __expf(-z));
}

__device__ __forceinline__ float softplus_f(float z) {
    return fmaxf(z, 0.0f) + log1pf(__expf(-fabsf(z)));
}

__device__ __forceinline__ short f2bf(float f) {
    union { float f; unsigned int u; } v; v.f = f;
    unsigned int r = v.u + 0x7FFF + ((v.u >> 16) & 1);   // round-nearest-even
    return (short)(r >> 16);
}

__device__ __forceinline__ bf16x8 pack8(float4 a, float4 b) {
    bf16x8 r;
    r[0] = f2bf(a.x); r[1] = f2bf(a.y); r[2] = f2bf(a.z); r[3] = f2bf(a.w);
    r[4] = f2bf(b.x); r[5] = f2bf(b.y); r[6] = f2bf(b.z); r[7] = f2bf(b.w);
    return r;
}

// ---------------------------------------------------------------------------
// Kernel 1: split-K up-projection. P[s] = up_x[:, s*512:(s+1)*512] @ W_up[s...]
// [8192,512] @ [512,256] -> fp32 partial [8192,256], no bias.
// 1024 blocks: 8 XCD x (16 bm x 4 bn x 2 split). Each XCD's A stripe = 4 MB.
// ---------------------------------------------------------------------------
__global__ __launch_bounds__(256) void gemm_up_splitk(
    const float* __restrict__ A,     // [M,1024]
    const float* __restrict__ W,     // [1024,256]
    float* __restrict__ P0,          // [M,256] partial split 0
    float* __restrict__ P1)          // [M,256] partial split 1
{
    __shared__ short Al[64 * LSTR];
    __shared__ short Bl[64 * LSTR];

    int lid = blockIdx.x;            // 0..1023
    int xcd = lid & 7;
    int slot = lid >> 3;             // 0..127
    int bm = xcd * 16 + (slot >> 3); // 0..127
    int r3 = slot & 7;
    int bn = r3 & 3;                 // 0..3
    int split = r3 >> 2;             // 0..1
    float* P = split ? P1 : P0;
    int k0 = split * 512;

    int tid = threadIdx.x;
    int w = tid >> 6, l = tid & 63;
    int lm = l & 15, q = l >> 4;
    int wm = (w & 1) * 32, wn = (w >> 1) * 32;

    f32x4 acc00 = {0,0,0,0}, acc01 = {0,0,0,0}, acc10 = {0,0,0,0}, acc11 = {0,0,0,0};

    int ar = tid >> 2, ak = (tid & 3) * 8;
    int bcol = tid & 63, bk = (tid >> 6) * 8;

    const float* Ag = A + (size_t)(bm * 64 + ar) * 1024 + k0 + ak;
    const float* Wg = W + (size_t)(k0) * TWO_D + (size_t)bn * 64 + bcol;

    for (int kt = 0; kt < 512; kt += 32) {
        float4 a0 = *(const float4*)(Ag + kt);
        float4 a1 = *(const float4*)(Ag + kt + 4);
        *(bf16x8*)&Al[ar * LSTR + ak] = pack8(a0, a1);

        float w0 = Wg[(size_t)(kt + bk + 0) * TWO_D];
        float w1 = Wg[(size_t)(kt + bk + 1) * TWO_D];
        float w2 = Wg[(size_t)(kt + bk + 2) * TWO_D];
        float w3 = Wg[(size_t)(kt + bk + 3) * TWO_D];
        float w4 = Wg[(size_t)(kt + bk + 4) * TWO_D];
        float w5 = Wg[(size_t)(kt + bk + 5) * TWO_D];
        float w6 = Wg[(size_t)(kt + bk + 6) * TWO_D];
        float w7 = Wg[(size_t)(kt + bk + 7) * TWO_D];
        *(bf16x8*)&Bl[bcol * LSTR + bk] =
            pack8(make_float4(w0, w1, w2, w3), make_float4(w4, w5, w6, w7));

        __syncthreads();

        bf16x8 af0 = *(bf16x8*)&Al[(wm + lm) * LSTR + q * 8];
        bf16x8 af1 = *(bf16x8*)&Al[(wm + 16 + lm) * LSTR + q * 8];
        bf16x8 bf0 = *(bf16x8*)&Bl[(wn + lm) * LSTR + q * 8];
        bf16x8 bf1 = *(bf16x8*)&Bl[(wn + 16 + lm) * LSTR + q * 8];

        acc00 = __builtin_amdgcn_mfma_f32_16x16x32_bf16(af0, bf0, acc00, 0, 0, 0);
        acc01 = __builtin_amdgcn_mfma_f32_16x16x32_bf16(af0, bf1, acc01, 0, 0, 0);
        acc10 = __builtin_amdgcn_mfma_f32_16x16x32_bf16(af1, bf0, acc10, 0, 0, 0);
        acc11 = __builtin_amdgcn_mfma_f32_16x16x32_bf16(af1, bf1, acc11, 0, 0, 0);

        __syncthreads();
    }

    #pragma unroll
    for (int i = 0; i < 4; i++) {
        int r0 = bm * 64 + wm + q * 4 + i;
        int r1 = r0 + 16;
        int c0 = bn * 64 + wn + lm;
        int c1 = c0 + 16;
        P[(size_t)r0 * TWO_D + c0] = acc00[i];
        P[(size_t)r0 * TWO_D + c1] = acc01[i];
        P[(size_t)r1 * TWO_D + c0] = acc10[i];
        P[(size_t)r1 * TWO_D + c1] = acc11[i];
    }
}

// ---------------------------------------------------------------------------
// Kernel 2: split-K reduce + bias, fused with causal conv K=3 + SiLU + gate.
// uu[r,c] = P0+P1+b_up. cols 0..127: x = silu(conv(uu)); cols 128..255:
// u[r,c] = uu (gate, the only part of u read downstream).
// ---------------------------------------------------------------------------
__global__ __launch_bounds__(256) void conv_gate_kernel(
    const float* __restrict__ P0,     // [M,256]
    const float* __restrict__ P1,     // [M,256]
    const float* __restrict__ b_up,   // [256]
    const float* __restrict__ conv_w, // [D,3]
    const float* __restrict__ conv_b, // [D]
    float* __restrict__ x,            // [M,128]
    float* __restrict__ u)            // [M,256] (right half written)
{
    int idx = blockIdx.x * 256 + threadIdx.x;   // over M*256
    int r = idx >> 8;
    int c = idx & 255;
    float bb = b_up[c];
    float p = P0[idx] + P1[idx] + bb;

    if (c >= 128) {                   // gate half
        u[idx] = p;
        return;
    }
    int t = r & (L_ - 1);
    float w0 = conv_w[c * 3 + 0];
    float w1 = conv_w[c * 3 + 1];
    float w2 = conv_w[c * 3 + 2];
    float v1 = (t >= 1) ? P0[idx - 256] + P1[idx - 256] + bb : 0.0f;
    float v0 = (t >= 2) ? P0[idx - 512] + P1[idx - 512] + bb : 0.0f;
    float z = fmaf(w0, v0, fmaf(w1, v1, fmaf(w2, p, conv_b[c])));
    x[(size_t)r * D_ + c] = silu_f(z);
}

// ---------------------------------------------------------------------------
// Kernel 3: fused delta/B/C projection as one bf16 MFMA GEMM:
// x[8192,128] @ [W_delta | W_B | W_C][128,256]; bn selects weights.
// ---------------------------------------------------------------------------
__global__ __launch_bounds__(256) void proj_mfma(
    const float* __restrict__ x,       // [M,128]
    const float* __restrict__ W_delta, const float* __restrict__ b_delta,
    const float* __restrict__ W_B,     const float* __restrict__ b_B,
    const float* __restrict__ W_C,     const float* __restrict__ b_C,
    float* __restrict__ delta,         // [M,128]
    float* __restrict__ Bm,            // [M,64]
    float* __restrict__ Cm)            // [M,64]
{
    __shared__ short Al[64 * LSTR];
    __shared__ short Bl[64 * LSTR];

    int lid = blockIdx.x;            // 0..511
    int xcd = lid & 7;
    int slot = lid >> 3;
    int bm = xcd * 16 + (slot >> 2);
    int bn = slot & 3;

    const float* Wsel; const float* bsel; int wstride;
    if (bn < 2)       { Wsel = W_delta + bn * 64; bsel = b_delta + bn * 64; wstride = 128; }
    else if (bn == 2) { Wsel = W_B;               bsel = b_B;               wstride = 64;  }
    else              { Wsel = W_C;               bsel = b_C;               wstride = 64;  }

    int tid = threadIdx.x;
    int w = tid >> 6, l = tid & 63;
    int lm = l & 15, q = l >> 4;
    int wm = (w & 1) * 32, wn = (w >> 1) * 32;

    f32x4 acc00 = {0,0,0,0}, acc01 = {0,0,0,0}, acc10 = {0,0,0,0}, acc11 = {0,0,0,0};

    int ar = tid >> 2, ak = (tid & 3) * 8;
    int bcol = tid & 63, bk = (tid >> 6) * 8;

    const float* Ag = x + (size_t)(bm * 64 + ar) * D_ + ak;
    const float* Wg = Wsel + bcol;

    for (int kt = 0; kt < 128; kt += 32) {
        float4 a0 = *(const float4*)(Ag + kt);
        float4 a1 = *(const float4*)(Ag + kt + 4);
        *(bf16x8*)&Al[ar * LSTR + ak] = pack8(a0, a1);

        float w0 = Wg[(size_t)(kt + bk + 0) * wstride];
        float w1 = Wg[(size_t)(kt + bk + 1) * wstride];
        float w2 = Wg[(size_t)(kt + bk + 2) * wstride];
        float w3 = Wg[(size_t)(kt + bk + 3) * wstride];
        float w4 = Wg[(size_t)(kt + bk + 4) * wstride];
        float w5 = Wg[(size_t)(kt + bk + 5) * wstride];
        float w6 = Wg[(size_t)(kt + bk + 6) * wstride];
        float w7 = Wg[(size_t)(kt + bk + 7) * wstride];
        *(bf16x8*)&Bl[bcol * LSTR + bk] =
            pack8(make_float4(w0, w1, w2, w3), make_float4(w4, w5, w6, w7));

        __syncthreads();

        bf16x8 af0 = *(bf16x8*)&Al[(wm + lm) * LSTR + q * 8];
        bf16x8 af1 = *(bf16x8*)&Al[(wm + 16 + lm) * LSTR + q * 8];
        bf16x8 bf0 = *(bf16x8*)&Bl[(wn + lm) * LSTR + q * 8];
        bf16x8 bf1 = *(bf16x8*)&Bl[(wn + 16 + lm) * LSTR + q * 8];

        acc00 = __builtin_amdgcn_mfma_f32_16x16x32_bf16(af0, bf0, acc00, 0, 0, 0);
        acc01 = __builtin_amdgcn_mfma_f32_16x16x32_bf16(af0, bf1, acc01, 0, 0, 0);
        acc10 = __builtin_amdgcn_mfma_f32_16x16x32_bf16(af1, bf0, acc10, 0, 0, 0);
        acc11 = __builtin_amdgcn_mfma_f32_16x16x32_bf16(af1, bf1, acc11, 0, 0, 0);

        __syncthreads();
    }

    #pragma unroll
    for (int i = 0; i < 4; i++) {
        int r0 = bm * 64 + wm + q * 4 + i;
        int r1 = r0 + 16;
        int c0 = wn + lm;
        int c1 = c0 + 16;
        float v00 = acc00[i] + bsel[c0];
        float v01 = acc01[i] + bsel[c1];
        float v10 = acc10[i] + bsel[c0];
        float v11 = acc11[i] + bsel[c1];
        if (bn < 2) {
            int cc0 = bn * 64 + c0, cc1 = bn * 64 + c1;
            delta[(size_t)r0 * D_ + cc0] = softplus_f(v00);
            delta[(size_t)r0 * D_ + cc1] = softplus_f(v01);
            delta[(size_t)r1 * D_ + cc0] = softplus_f(v10);
            delta[(size_t)r1 * D_ + cc1] = softplus_f(v11);
        } else if (bn == 2) {
            Bm[(size_t)r0 * N_ + c0] = v00;
            Bm[(size_t)r0 * N_ + c1] = v01;
            Bm[(size_t)r1 * N_ + c0] = v10;
            Bm[(size_t)r1 * N_ + c1] = v11;
        } else {
            Cm[(size_t)r0 * N_ + c0] = v00;
            Cm[(size_t)r0 * N_ + c1] = v01;
            Cm[(size_t)r1 * N_ + c0] = v10;
            Cm[(size_t)r1 * N_ + c1] = v11;
        }
    }
}

// ---------------------------------------------------------------------------
// Kernel 4a: summary pass — per (b, d-quad, chunk) wave, 4 states per lane.
// ---------------------------------------------------------------------------
template<int LOG_NC>
__global__ __launch_bounds__(256) void scan_sumA(
    const float* __restrict__ delta,   // [M,D]
    const float* __restrict__ x,       // [M,D]
    const float* __restrict__ Bm,      // [M,N]
    const float* __restrict__ A_log,   // [D,N]
    float* __restrict__ ch_aprod,      // [B,D,NC,N]
    float* __restrict__ ch_h)          // [B,D,NC,N]
{
    constexpr int NCt = 1 << LOG_NC;
    constexpr int TCt = L_ >> LOG_NC;

    int wid = blockIdx.x * 4 + (threadIdx.x >> 6);
    int l = threadIdx.x & 63;
    int g = l >> 4, j = l & 15;
    int c = wid & (NCt - 1);
    int dq = (wid >> LOG_NC) & 31;
    int b = wid >> (LOG_NC + 5);
    int d = dq * 4 + g;

    const float LOG2E = 1.44269504089f;
    float4 Ar = *(const float4*)&A_log[d * N_ + j * 4];
    float Ai0 = -__expf(Ar.x) * LOG2E;
    float Ai1 = -__expf(Ar.y) * LOG2E;
    float Ai2 = -__expf(Ar.z) * LOG2E;
    float Ai3 = -__expf(Ar.w) * LOG2E;

    size_t row0 = (size_t)b * L_ + c * TCt;
    const float* dp = delta + row0 * D_ + d;
    const float* xp = x     + row0 * D_ + d;
    const float* bp = Bm    + row0 * N_ + j * 4;

    float h0 = 0, h1 = 0, h2 = 0, h3 = 0;
    float S = 0;

    #pragma unroll 8
    for (int t = 0; t < TCt; t++) {
        float dl = dp[t * D_];
        float xv = xp[t * D_];
        float4 bv = *(const float4*)&bp[t * N_];
        float e0 = exp2f(dl * Ai0);
        float e1 = exp2f(dl * Ai1);
        float e2 = exp2f(dl * Ai2);
        float e3 = exp2f(dl * Ai3);
        float dbx = dl * xv;
        h0 = fmaf(e0, h0, dbx * bv.x);
        h1 = fmaf(e1, h1, dbx * bv.y);
        h2 = fmaf(e2, h2, dbx * bv.z);
        h3 = fmaf(e3, h3, dbx * bv.w);
        S += dl;
    }

    size_t ci = (((size_t)b * D_ + d) * NCt + c) * N_ + j * 4;
    *(float4*)&ch_aprod[ci] = make_float4(exp2f(Ai0 * S), exp2f(Ai1 * S),
                                          exp2f(Ai2 * S), exp2f(Ai3 * S));
    *(float4*)&ch_h[ci]     = make_float4(h0, h1, h2, h3);
}

// ---------------------------------------------------------------------------
// Kernel 4b: serial prefix over NC chunk summaries, per (b,d,n).
// ---------------------------------------------------------------------------
template<int LOG_NC>
__global__ __launch_bounds__(256) void scan_prefix(
    float* __restrict__ aprod_hin,     // in: chunk aprod; out: hin
    const float* __restrict__ ch_h)
{
    constexpr int NCt = 1 << LOG_NC;
    int idx = blockIdx.x * 256 + threadIdx.x;   // B*D*N = 32768 exact
    int n = idx & 63;
    int rest = idx >> 6;
    size_t base = (size_t)rest * NCt * N_ + n;
    float h = 0.0f;
    #pragma unroll 8
    for (int c = 0; c < NCt; c++) {
        size_t o = base + (size_t)c * N_;
        float a  = aprod_hin[o];
        float hh = ch_h[o];
        aprod_hin[o] = h;
        h = fmaf(a, h, hh);
    }
}

// ---------------------------------------------------------------------------
// Kernel 4c: output pass — all chunks, h seeded from hin (zero for chunk 0).
// ---------------------------------------------------------------------------
template<int LOG_NC>
__global__ __launch_bounds__(256) void scan_outB(
    const float* __restrict__ delta,   // [M,D]
    const float* __restrict__ x,       // [M,D]
    const float* __restrict__ Bm,      // [M,N]
    const float* __restrict__ Cm,      // [M,N]
    const float* __restrict__ A_log,   // [D,N]
    const float* __restrict__ D_skip,  // [D]
    const float* __restrict__ hin,     // [B,D,NC,N]
    float* __restrict__ y)             // [M,D]
{
    constexpr int NCt = 1 << LOG_NC;
    constexpr int TCt = L_ >> LOG_NC;

    int wid = blockIdx.x * 4 + (threadIdx.x >> 6);
    int l = threadIdx.x & 63;
    int g = l >> 4, j = l & 15;
    int c = wid & (NCt - 1);
    int dq = (wid >> LOG_NC) & 31;
    int b = wid >> (LOG_NC + 5);
    int d = dq * 4 + g;

    const float LOG2E = 1.44269504089f;
    float4 Ar = *(const float4*)&A_log[d * N_ + j * 4];
    float Ai0 = -__expf(Ar.x) * LOG2E;
    float Ai1 = -__expf(Ar.y) * LOG2E;
    float Ai2 = -__expf(Ar.z) * LOG2E;
    float Ai3 = -__expf(Ar.w) * LOG2E;
    float dsk = D_skip[d];

    float4 hv = *(const float4*)&hin[(((size_t)b * D_ + d) * NCt + c) * N_ + j * 4];
    float h0 = hv.x, h1 = hv.y, h2 = hv.z, h3 = hv.w;

    size_t row0 = (size_t)b * L_ + c * TCt;
    const float* dp = delta + row0 * D_ + d;
    const float* xp = x     + row0 * D_ + d;
    const float* bp = Bm    + row0 * N_ + j * 4;
    const float* cp = Cm    + row0 * N_ + j * 4;
    float*       yp = y     + row0 * D_ + d;

    #pragma unroll 8
    for (int t = 0; t < TCt; t++) {
        float dl = dp[t * D_];
        float xv = xp[t * D_];
        float4 bv = *(const float4*)&bp[t * N_];
        float4 cv = *(const float4*)&cp[t * N_];
        float e0 = exp2f(dl * Ai0);
        float e1 = exp2f(dl * Ai1);
        float e2 = exp2f(dl * Ai2);
        float e3 = exp2f(dl * Ai3);
        float dbx = dl * xv;
        h0 = fmaf(e0, h0, dbx * bv.x);
        h1 = fmaf(e1, h1, dbx * bv.y);
        h2 = fmaf(e2, h2, dbx * bv.z);
        h3 = fmaf(e3, h3, dbx * bv.w);
        float p = fmaf(h0, cv.x, fmaf(h1, cv.y, fmaf(h2, cv.z, h3 * cv.w)));
        p += __shfl_xor(p, 1, 64);
        p += __shfl_xor(p, 2, 64);
        p += __shfl_xor(p, 4, 64);
        p += __shfl_xor(p, 8, 64);
        if (j == 0) yp[t * D_] = fmaf(dsk, xv, p);
    }
}

// ---------------------------------------------------------------------------
// Kernel 5: out = (y * silu(u_right)) @ W_down + b_down
// ---------------------------------------------------------------------------
__global__ __launch_bounds__(256) void gemm_down_mfma(
    const float* __restrict__ y,     // [M,128]
    const float* __restrict__ u,     // [M,256] right half gates
    const float* __restrict__ W,     // [128,1024]
    const float* __restrict__ bias,  // [1024]
    float* __restrict__ out)         // [M,1024]
{
    __shared__ short Al[64 * LSTR];
    __shared__ short Bl[64 * LSTR];

    int lid = blockIdx.x;            // 0..2047
    int xcd = lid & 7;
    int slot = lid >> 3;             // 0..255
    int bm = xcd * 16 + (slot >> 4); // 0..127
    int bn = slot & 15;              // 0..15

    int tid = threadIdx.x;
    int w = tid >> 6, l = tid & 63;
    int lm = l & 15, q = l >> 4;
    int wm = (w & 1) * 32, wn = (w >> 1) * 32;

    f32x4 acc00 = {0,0,0,0}, acc01 = {0,0,0,0}, acc10 = {0,0,0,0}, acc11 = {0,0,0,0};

    int ar = tid >> 2, ak = (tid & 3) * 8;
    int bcol = tid & 63, bk = (tid >> 6) * 8;

    const float* Yg = y + (size_t)(bm * 64 + ar) * D_ + ak;
    const float* Ug = u + (size_t)(bm * 64 + ar) * TWO_D + D_ + ak;
    const float* Wg = W + (size_t)bn * 64 + bcol;

    for (int kt = 0; kt < 128; kt += 32) {
        float4 y0 = *(const float4*)(Yg + kt);
        float4 y1 = *(const float4*)(Yg + kt + 4);
        float4 g0 = *(const float4*)(Ug + kt);
        float4 g1 = *(const float4*)(Ug + kt + 4);
        float4 a0 = make_float4(y0.x * silu_f(g0.x), y0.y * silu_f(g0.y),
                                y0.z * silu_f(g0.z), y0.w * silu_f(g0.w));
        float4 a1 = make_float4(y1.x * silu_f(g1.x), y1.y * silu_f(g1.y),
                                y1.z * silu_f(g1.z), y1.w * silu_f(g1.w));
        *(bf16x8*)&Al[ar * LSTR + ak] = pack8(a0, a1);

        float w0 = Wg[(size_t)(kt + bk + 0) * R_];
        float w1 = Wg[(size_t)(kt + bk + 1) * R_];
        float w2 = Wg[(size_t)(kt + bk + 2) * R_];
        float w3 = Wg[(size_t)(kt + bk + 3) * R_];
        float w4 = Wg[(size_t)(kt + bk + 4) * R_];
        float w5 = Wg[(size_t)(kt + bk + 5) * R_];
        float w6 = Wg[(size_t)(kt + bk + 6) * R_];
        float w7 = Wg[(size_t)(kt + bk + 7) * R_];
        *(bf16x8*)&Bl[bcol * LSTR + bk] =
            pack8(make_float4(w0, w1, w2, w3), make_float4(w4, w5, w6, w7));

        __syncthreads();

        bf16x8 af0 = *(bf16x8*)&Al[(wm + lm) * LSTR + q * 8];
        bf16x8 af1 = *(bf16x8*)&Al[(wm + 16 + lm) * LSTR + q * 8];
        bf16x8 bf0 = *(bf16x8*)&Bl[(wn + lm) * LSTR + q * 8];
        bf16x8 bf1 = *(bf16x8*)&Bl[(wn + 16 + lm) * LSTR + q * 8];

        acc00 = __builtin_amdgcn_mfma_f32_16x16x32_bf16(af0, bf0, acc00, 0, 0, 0);
        acc01 = __builtin_amdgcn_mfma_f32_16x16x32_bf16(af0, bf1, acc01, 0, 0, 0);
        acc10 = __builtin_amdgcn_mfma_f32_16x16x32_bf16(af1, bf0, acc10, 0, 0, 0);
        acc11 = __builtin_amdgcn_mfma_f32_16x16x32_bf16(af1, bf1, acc11, 0, 0, 0);

        __syncthreads();
    }

    #pragma unroll
    for (int i = 0; i < 4; i++) {
        int r0 = bm * 64 + wm + q * 4 + i;
        int r1 = r0 + 16;
        int c0 = bn * 64 + wn + lm;
        int c1 = c0 + 16;
        out[(size_t)r0 * R_ + c0] = acc00[i] + bias[c0];
        out[(size_t)r0 * R_ + c1] = acc01[i] + bias[c1];
        out[(size_t)r1 * R_ + c0] = acc10[i] + bias[c0];
        out[(size_t)r1 * R_ + c1] = acc11[i] + bias[c1];
    }
}

// ---------------------------------------------------------------------------
extern "C" void kernel_launch(void* const* d_in, const int* in_sizes, int n_in,
                              void* d_out, int out_size, void* d_ws, size_t ws_size,
                              hipStream_t stream)
{
    const float* up_x    = (const float*)d_in[0];
    const float* W_up    = (const float*)d_in[1];
    const float* b_up    = (const float*)d_in[2];
    const float* conv_w  = (const float*)d_in[3];
    const float* conv_b  = (const float*)d_in[4];
    const float* W_delta = (const float*)d_in[5];
    const float* b_delta = (const float*)d_in[6];
    const float* W_B     = (const float*)d_in[7];
    const float* b_B     = (const float*)d_in[8];
    const float* W_C     = (const float*)d_in[9];
    const float* b_C     = (const float*)d_in[10];
    const float* A_log   = (const float*)d_in[11];
    const float* D_skip  = (const float*)d_in[12];
    const float* W_down  = (const float*)d_in[13];
    const float* b_down  = (const float*)d_in[14];

    float* out = (float*)d_out;
    float* ws  = (float*)d_ws;

    // fixed workspace (floats): u, x, delta, Bm, Cm, y, ch...
    float* u     = ws;                          // M*2D (only right half used)
    float* x     = u + (size_t)M_ * TWO_D;      // M*D
    float* delta = x + (size_t)M_ * D_;         // M*D
    float* Bm    = delta + (size_t)M_ * D_;     // M*N
    float* Cm    = Bm + (size_t)M_ * N_;        // M*N
    float* y     = Cm + (size_t)M_ * N_;        // M*D
    float* ch_aprod = y + (size_t)M_ * D_;      // B*D*NC*N (NC-dependent)
    bool big = ws_size >= (size_t)41943040;

    // split-K partials alias regions that are dead until after conv_gate:
    // P0 spans delta+Bm+Cm (= M*2D floats exactly); P1 spans y + ch head.
    float* P0 = delta;
    float* P1 = y;

    // 1. split-K up-projection (bf16 MFMA, 1024 blocks, XCD-swizzled)
    gemm_up_splitk<<<1024, 256, 0, stream>>>(up_x, W_up, P0, P1);

    // 2. reduce + bias + causal conv + silu + gate extraction
    conv_gate_kernel<<<(M_ * TWO_D) / 256, 256, 0, stream>>>(
        P0, P1, b_up, conv_w, conv_b, x, u);

    // 3. fused delta/B/C projection (bf16 MFMA, XCD-swizzled)
    proj_mfma<<<4 * (M_ / 64), 256, 0, stream>>>(
        x, W_delta, b_delta, W_B, b_B, W_C, b_C, delta, Bm, Cm);

    // 4. chunked selective scan: summaries -> prefix -> output
    if (big) {
        constexpr int LNC = 6;                       // NC=64, TC=32
        float* ch_h = ch_aprod + (size_t)B_ * D_ * (1 << LNC) * N_;
        scan_sumA<LNC><<<(B_ * (D_ / 4) * (1 << LNC)) / 4, 256, 0, stream>>>(
            delta, x, Bm, A_log, ch_aprod, ch_h);
        scan_prefix<LNC><<<(B_ * D_ * N_) / 256, 256, 0, stream>>>(
            ch_aprod, ch_h);
        scan_outB<LNC><<<(B_ * (D_ / 4) * (1 << LNC)) / 4, 256, 0, stream>>>(
            delta, x, Bm, Cm, A_log, D_skip, ch_aprod, y);
    } else {
        constexpr int LNC = 5;                       // NC=32, TC=64
        float* ch_h = ch_aprod + (size_t)B_ * D_ * (1 << LNC) * N_;
        scan_sumA<LNC><<<(B_ * (D_ / 4) * (1 << LNC)) / 4, 256, 0, stream>>>(
            delta, x, Bm, A_log, ch_aprod, ch_h);
        scan_prefix<LNC><<<(B_ * D_ * N_) / 256, 256, 0, stream>>>(
            ch_aprod, ch_h);
        scan_outB<LNC><<<(B_ * (D_ / 4) * (1 << LNC)) / 4, 256, 0, stream>>>(
            delta, x, Bm, Cm, A_log, D_skip, ch_aprod, y);
    }

    // 5. gate + down-projection GEMM (bf16 MFMA, XCD-swizzled)
    gemm_down_mfma<<<16 * (M_ / 64), 256, 0, stream>>>(
        y, u, W_down, b_down, out);
}

// Round 11
// 218.642 us; speedup vs baseline: 5.9687x; 1.0001x over previous
//
#include <hip/hip_runtime.h>
#include <math.h>

// Problem constants (from reference)
#define B_ 4
#define L_ 2048
#define R_ 1024
#define D_ 128      // ssm input dim
#define N_ 64       // state size
#define TWO_D 256   // 2*D
#define M_ (B_*L_)  // 8192 rows

// scan chunking: NC=64 chunks of TC=32 (round-8 proven config)
#define LNC 6
#define NC 64

// LDS row stride in shorts for 32-wide K tiles: 68 shorts = 34 dwords,
// 34 mod 32 = 2 -> <=2-way bank aliasing (free on CDNA4).
#define LSTR 68
// LDS row stride for full 128-K A tile: 136 shorts = 272 B (16B-aligned rows).
#define LSTRX 136

typedef __attribute__((ext_vector_type(8))) short bf16x8;
typedef __attribute__((ext_vector_type(4))) float f32x4;

__device__ __forceinline__ float silu_f(float z) {
    return z / (1.0f + __expf(-z));
}

__device__ __forceinline__ float softplus_f(float z) {
    return fmaxf(z, 0.0f) + log1pf(__expf(-fabsf(z)));
}

__device__ __forceinline__ short f2bf(float f) {
    union { float f; unsigned int u; } v; v.f = f;
    unsigned int r = v.u + 0x7FFF + ((v.u >> 16) & 1);   // round-nearest-even
    return (short)(r >> 16);
}

__device__ __forceinline__ bf16x8 pack8(float4 a, float4 b) {
    bf16x8 r;
    r[0] = f2bf(a.x); r[1] = f2bf(a.y); r[2] = f2bf(a.z); r[3] = f2bf(a.w);
    r[4] = f2bf(b.x); r[5] = f2bf(b.y); r[6] = f2bf(b.z); r[7] = f2bf(b.w);
    return r;
}

// ---------------------------------------------------------------------------
// Kernel 1: split-K up-projection. P[s] = up_x[:, s*512:(s+1)*512] @ W_up
// 1024 blocks: 8 XCD x (16 bm x 4 bn x 2 split). fp32 partials, no bias.
// P0/P1 are DEDICATED buffers (aliasing them with delta/y raced in round 9).
// ---------------------------------------------------------------------------
__global__ __launch_bounds__(256) void gemm_up_splitk(
    const float* __restrict__ A,     // [M,1024]
    const float* __restrict__ W,     // [1024,256]
    float* __restrict__ P0,          // [M,256]
    float* __restrict__ P1)          // [M,256]
{
    __shared__ short Al[64 * LSTR];
    __shared__ short Bl[64 * LSTR];

    int lid = blockIdx.x;
    int xcd = lid & 7;
    int slot = lid >> 3;
    int bm = xcd * 16 + (slot >> 3);
    int r3 = slot & 7;
    int bn = r3 & 3;
    int split = r3 >> 2;
    float* P = split ? P1 : P0;
    int k0 = split * 512;

    int tid = threadIdx.x;
    int w = tid >> 6, l = tid & 63;
    int lm = l & 15, q = l >> 4;
    int wm = (w & 1) * 32, wn = (w >> 1) * 32;

    f32x4 acc00 = {0,0,0,0}, acc01 = {0,0,0,0}, acc10 = {0,0,0,0}, acc11 = {0,0,0,0};

    int ar = tid >> 2, ak = (tid & 3) * 8;
    int bcol = tid & 63, bk = (tid >> 6) * 8;

    const float* Ag = A + (size_t)(bm * 64 + ar) * 1024 + k0 + ak;
    const float* Wg = W + (size_t)k0 * TWO_D + (size_t)bn * 64 + bcol;

    for (int kt = 0; kt < 512; kt += 32) {
        float4 a0 = *(const float4*)(Ag + kt);
        float4 a1 = *(const float4*)(Ag + kt + 4);
        *(bf16x8*)&Al[ar * LSTR + ak] = pack8(a0, a1);

        float w0 = Wg[(size_t)(kt + bk + 0) * TWO_D];
        float w1 = Wg[(size_t)(kt + bk + 1) * TWO_D];
        float w2 = Wg[(size_t)(kt + bk + 2) * TWO_D];
        float w3 = Wg[(size_t)(kt + bk + 3) * TWO_D];
        float w4 = Wg[(size_t)(kt + bk + 4) * TWO_D];
        float w5 = Wg[(size_t)(kt + bk + 5) * TWO_D];
        float w6 = Wg[(size_t)(kt + bk + 6) * TWO_D];
        float w7 = Wg[(size_t)(kt + bk + 7) * TWO_D];
        *(bf16x8*)&Bl[bcol * LSTR + bk] =
            pack8(make_float4(w0, w1, w2, w3), make_float4(w4, w5, w6, w7));

        __syncthreads();

        bf16x8 af0 = *(bf16x8*)&Al[(wm + lm) * LSTR + q * 8];
        bf16x8 af1 = *(bf16x8*)&Al[(wm + 16 + lm) * LSTR + q * 8];
        bf16x8 bf0 = *(bf16x8*)&Bl[(wn + lm) * LSTR + q * 8];
        bf16x8 bf1 = *(bf16x8*)&Bl[(wn + 16 + lm) * LSTR + q * 8];

        acc00 = __builtin_amdgcn_mfma_f32_16x16x32_bf16(af0, bf0, acc00, 0, 0, 0);
        acc01 = __builtin_amdgcn_mfma_f32_16x16x32_bf16(af0, bf1, acc01, 0, 0, 0);
        acc10 = __builtin_amdgcn_mfma_f32_16x16x32_bf16(af1, bf0, acc10, 0, 0, 0);
        acc11 = __builtin_amdgcn_mfma_f32_16x16x32_bf16(af1, bf1, acc11, 0, 0, 0);

        __syncthreads();
    }

    #pragma unroll
    for (int i = 0; i < 4; i++) {
        int r0 = bm * 64 + wm + q * 4 + i;
        int r1 = r0 + 16;
        int c0 = bn * 64 + wn + lm;
        int c1 = c0 + 16;
        P[(size_t)r0 * TWO_D + c0] = acc00[i];
        P[(size_t)r0 * TWO_D + c1] = acc01[i];
        P[(size_t)r1 * TWO_D + c0] = acc10[i];
        P[(size_t)r1 * TWO_D + c1] = acc11[i];
    }
}

// ---------------------------------------------------------------------------
// Kernel 2: fused (split-K reduce + bias) + causal conv K=3 + SiLU + gate +
// delta/B/C MFMA projection. 512 blocks = 8 XCD x 16 bm x 4 bn.
// ---------------------------------------------------------------------------
__global__ __launch_bounds__(256) void convproj_mfma(
    const float* __restrict__ P0,      // [M,256]
    const float* __restrict__ P1,      // [M,256]
    const float* __restrict__ b_up,    // [256]
    const float* __restrict__ conv_w,  // [D,3]
    const float* __restrict__ conv_b,  // [D]
    const float* __restrict__ W_delta, const float* __restrict__ b_delta,
    const float* __restrict__ W_B,     const float* __restrict__ b_B,
    const float* __restrict__ W_C,     const float* __restrict__ b_C,
    float* __restrict__ x,             // [M,128] fp32 (for scan)
    float* __restrict__ u,             // [M,256] (right half written)
    float* __restrict__ delta,         // [M,128]
    float* __restrict__ Bm,            // [M,64]
    float* __restrict__ Cm)            // [M,64]
{
    __shared__ float uu[66 * 128];     // rows -2..63, conv cols
    __shared__ short Xl[64 * LSTRX];   // bf16 A operand, full K=128
    __shared__ short Bl[64 * LSTR];

    int lid = blockIdx.x;
    int xcd = lid & 7;
    int slot = lid >> 3;
    int bm = xcd * 16 + (slot >> 2);
    int bn = slot & 3;
    int tid = threadIdx.x;

    bool seq_start = (bm & 31) == 0;   // tile starts at t==0 of a sequence

    // ---- stage uu = P0+P1+b_up for rows bm*64-2 .. bm*64+63, cols 0..127 ----
    #pragma unroll
    for (int i = 0; i < 9; i++) {
        int fi = tid + i * 256;        // float4 index, 2112 total
        if (fi < 2112) {
            int row = fi >> 5;         // 0..65
            int c4 = (fi & 31) * 4;    // 0..124
            int gr = bm * 64 + row - 2;
            float4 v;
            if (seq_start && row < 2) {
                v = make_float4(0.f, 0.f, 0.f, 0.f);
            } else {
                size_t gi = (size_t)gr * TWO_D + c4;
                float4 p0 = *(const float4*)&P0[gi];
                float4 p1 = *(const float4*)&P1[gi];
                float4 bb = *(const float4*)&b_up[c4];
                v = make_float4(p0.x + p1.x + bb.x, p0.y + p1.y + bb.y,
                                p0.z + p1.z + bb.z, p0.w + p1.w + bb.w);
            }
            *(float4*)&uu[fi * 4] = v;
        }
    }

    // ---- gate half (bn==1 writes u[:,128:256]) ----
    if (bn == 1) {
        #pragma unroll
        for (int i = 0; i < 8; i++) {
            int fi = tid + i * 256;    // 2048 float4s
            int row = fi >> 5;
            int c4 = (fi & 31) * 4 + 128;
            int gr = bm * 64 + row;
            size_t gi = (size_t)gr * TWO_D + c4;
            float4 p0 = *(const float4*)&P0[gi];
            float4 p1 = *(const float4*)&P1[gi];
            float4 bb = *(const float4*)&b_up[c4];
            *(float4*)&u[gi] = make_float4(p0.x + p1.x + bb.x, p0.y + p1.y + bb.y,
                                           p0.z + p1.z + bb.z, p0.w + p1.w + bb.w);
        }
    }
    __syncthreads();

    // ---- conv + silu -> Xl (bf16) and (bn==0) x global (fp32) ----
    #pragma unroll
    for (int i = 0; i < 8; i++) {
        int fi = tid + i * 256;        // 2048 float4 outputs
        int row = fi >> 5;             // 0..63
        int c4 = (fi & 31) * 4;
        float4 v2 = *(const float4*)&uu[(row + 2) * 128 + c4];
        float4 v1 = *(const float4*)&uu[(row + 1) * 128 + c4];
        float4 v0 = *(const float4*)&uu[(row + 0) * 128 + c4];
        float4 z;
        {
            float w0 = conv_w[(c4 + 0) * 3 + 0], w1 = conv_w[(c4 + 0) * 3 + 1], w2 = conv_w[(c4 + 0) * 3 + 2];
            z.x = silu_f(fmaf(w0, v0.x, fmaf(w1, v1.x, fmaf(w2, v2.x, conv_b[c4 + 0]))));
        }
        {
            float w0 = conv_w[(c4 + 1) * 3 + 0], w1 = conv_w[(c4 + 1) * 3 + 1], w2 = conv_w[(c4 + 1) * 3 + 2];
            z.y = silu_f(fmaf(w0, v0.y, fmaf(w1, v1.y, fmaf(w2, v2.y, conv_b[c4 + 1]))));
        }
        {
            float w0 = conv_w[(c4 + 2) * 3 + 0], w1 = conv_w[(c4 + 2) * 3 + 1], w2 = conv_w[(c4 + 2) * 3 + 2];
            z.z = silu_f(fmaf(w0, v0.z, fmaf(w1, v1.z, fmaf(w2, v2.z, conv_b[c4 + 2]))));
        }
        {
            float w0 = conv_w[(c4 + 3) * 3 + 0], w1 = conv_w[(c4 + 3) * 3 + 1], w2 = conv_w[(c4 + 3) * 3 + 2];
            z.w = silu_f(fmaf(w0, v0.w, fmaf(w1, v1.w, fmaf(w2, v2.w, conv_b[c4 + 3]))));
        }
        short4 zb;
        zb.x = f2bf(z.x); zb.y = f2bf(z.y); zb.z = f2bf(z.z); zb.w = f2bf(z.w);
        *(short4*)&Xl[row * LSTRX + c4] = zb;
        if (bn == 0) {
            int gr = bm * 64 + row;
            *(float4*)&x[(size_t)gr * D_ + c4] = z;
        }
    }

    // ---- weight select ----
    const float* Wsel; const float* bsel; int wstride;
    if (bn < 2)       { Wsel = W_delta + bn * 64; bsel = b_delta + bn * 64; wstride = 128; }
    else if (bn == 2) { Wsel = W_B;               bsel = b_B;               wstride = 64;  }
    else              { Wsel = W_C;               bsel = b_C;               wstride = 64;  }

    int w = tid >> 6, l = tid & 63;
    int lm = l & 15, q = l >> 4;
    int wm = (w & 1) * 32, wn = (w >> 1) * 32;

    f32x4 acc00 = {0,0,0,0}, acc01 = {0,0,0,0}, acc10 = {0,0,0,0}, acc11 = {0,0,0,0};

    int bcol = tid & 63, bk = (tid >> 6) * 8;
    const float* Wg = Wsel + bcol;

    __syncthreads();

    for (int kt = 0; kt < 128; kt += 32) {
        float w0 = Wg[(size_t)(kt + bk + 0) * wstride];
        float w1 = Wg[(size_t)(kt + bk + 1) * wstride];
        float w2 = Wg[(size_t)(kt + bk + 2) * wstride];
        float w3 = Wg[(size_t)(kt + bk + 3) * wstride];
        float w4 = Wg[(size_t)(kt + bk + 4) * wstride];
        float w5 = Wg[(size_t)(kt + bk + 5) * wstride];
        float w6 = Wg[(size_t)(kt + bk + 6) * wstride];
        float w7 = Wg[(size_t)(kt + bk + 7) * wstride];
        *(bf16x8*)&Bl[bcol * LSTR + bk] =
            pack8(make_float4(w0, w1, w2, w3), make_float4(w4, w5, w6, w7));

        __syncthreads();

        bf16x8 af0 = *(bf16x8*)&Xl[(wm + lm) * LSTRX + kt + q * 8];
        bf16x8 af1 = *(bf16x8*)&Xl[(wm + 16 + lm) * LSTRX + kt + q * 8];
        bf16x8 bf0 = *(bf16x8*)&Bl[(wn + lm) * LSTR + q * 8];
        bf16x8 bf1 = *(bf16x8*)&Bl[(wn + 16 + lm) * LSTR + q * 8];

        acc00 = __builtin_amdgcn_mfma_f32_16x16x32_bf16(af0, bf0, acc00, 0, 0, 0);
        acc01 = __builtin_amdgcn_mfma_f32_16x16x32_bf16(af0, bf1, acc01, 0, 0, 0);
        acc10 = __builtin_amdgcn_mfma_f32_16x16x32_bf16(af1, bf0, acc10, 0, 0, 0);
        acc11 = __builtin_amdgcn_mfma_f32_16x16x32_bf16(af1, bf1, acc11, 0, 0, 0);

        __syncthreads();
    }

    #pragma unroll
    for (int i = 0; i < 4; i++) {
        int r0 = bm * 64 + wm + q * 4 + i;
        int r1 = r0 + 16;
        int c0 = wn + lm;
        int c1 = c0 + 16;
        float v00 = acc00[i] + bsel[c0];
        float v01 = acc01[i] + bsel[c1];
        float v10 = acc10[i] + bsel[c0];
        float v11 = acc11[i] + bsel[c1];
        if (bn < 2) {
            int cc0 = bn * 64 + c0, cc1 = bn * 64 + c1;
            delta[(size_t)r0 * D_ + cc0] = softplus_f(v00);
            delta[(size_t)r0 * D_ + cc1] = softplus_f(v01);
            delta[(size_t)r1 * D_ + cc0] = softplus_f(v10);
            delta[(size_t)r1 * D_ + cc1] = softplus_f(v11);
        } else if (bn == 2) {
            Bm[(size_t)r0 * N_ + c0] = v00;
            Bm[(size_t)r0 * N_ + c1] = v01;
            Bm[(size_t)r1 * N_ + c0] = v10;
            Bm[(size_t)r1 * N_ + c1] = v11;
        } else {
            Cm[(size_t)r0 * N_ + c0] = v00;
            Cm[(size_t)r0 * N_ + c1] = v01;
            Cm[(size_t)r1 * N_ + c0] = v10;
            Cm[(size_t)r1 * N_ + c1] = v11;
        }
    }
}

// ---------------------------------------------------------------------------
// Kernel 3a: summary pass — per (b, d-quad, chunk) wave, 4 states per lane.
// ---------------------------------------------------------------------------
__global__ __launch_bounds__(256) void scan_sumA(
    const float* __restrict__ delta,   // [M,D]
    const float* __restrict__ x,       // [M,D]
    const float* __restrict__ Bm,      // [M,N]
    const float* __restrict__ A_log,   // [D,N]
    float* __restrict__ ch_aprod,      // [B,D,NC,N]
    float* __restrict__ ch_h)          // [B,D,NC,N]
{
    constexpr int TCt = L_ >> LNC;

    int wid = blockIdx.x * 4 + (threadIdx.x >> 6);
    int l = threadIdx.x & 63;
    int g = l >> 4, j = l & 15;
    int c = wid & (NC - 1);
    int dq = (wid >> LNC) & 31;
    int b = wid >> (LNC + 5);
    int d = dq * 4 + g;

    const float LOG2E = 1.44269504089f;
    float4 Ar = *(const float4*)&A_log[d * N_ + j * 4];
    float Ai0 = -__expf(Ar.x) * LOG2E;
    float Ai1 = -__expf(Ar.y) * LOG2E;
    float Ai2 = -__expf(Ar.z) * LOG2E;
    float Ai3 = -__expf(Ar.w) * LOG2E;

    size_t row0 = (size_t)b * L_ + c * TCt;
    const float* dp = delta + row0 * D_ + d;
    const float* xp = x     + row0 * D_ + d;
    const float* bp = Bm    + row0 * N_ + j * 4;

    float h0 = 0, h1 = 0, h2 = 0, h3 = 0;
    float S = 0;

    #pragma unroll 8
    for (int t = 0; t < TCt; t++) {
        float dl = dp[t * D_];
        float xv = xp[t * D_];
        float4 bv = *(const float4*)&bp[t * N_];
        float e0 = exp2f(dl * Ai0);
        float e1 = exp2f(dl * Ai1);
        float e2 = exp2f(dl * Ai2);
        float e3 = exp2f(dl * Ai3);
        float dbx = dl * xv;
        h0 = fmaf(e0, h0, dbx * bv.x);
        h1 = fmaf(e1, h1, dbx * bv.y);
        h2 = fmaf(e2, h2, dbx * bv.z);
        h3 = fmaf(e3, h3, dbx * bv.w);
        S += dl;
    }

    size_t ci = (((size_t)b * D_ + d) * NC + c) * N_ + j * 4;
    *(float4*)&ch_aprod[ci] = make_float4(exp2f(Ai0 * S), exp2f(Ai1 * S),
                                          exp2f(Ai2 * S), exp2f(Ai3 * S));
    *(float4*)&ch_h[ci]     = make_float4(h0, h1, h2, h3);
}

// ---------------------------------------------------------------------------
// Kernel 3b: serial prefix over NC chunk summaries, per (b,d,n).
// ---------------------------------------------------------------------------
__global__ __launch_bounds__(256) void scan_prefix(
    float* __restrict__ aprod_hin,     // in: chunk aprod; out: hin
    const float* __restrict__ ch_h)
{
    int idx = blockIdx.x * 256 + threadIdx.x;   // B*D*N = 32768 exact
    int n = idx & 63;
    int rest = idx >> 6;
    size_t base = (size_t)rest * NC * N_ + n;
    float h = 0.0f;
    #pragma unroll 8
    for (int c = 0; c < NC; c++) {
        size_t o = base + (size_t)c * N_;
        float a  = aprod_hin[o];
        float hh = ch_h[o];
        aprod_hin[o] = h;
        h = fmaf(a, h, hh);
    }
}

// ---------------------------------------------------------------------------
// Kernel 3c: output pass — all chunks, h seeded from hin (zero for chunk 0).
// ---------------------------------------------------------------------------
__global__ __launch_bounds__(256) void scan_outB(
    const float* __restrict__ delta,   // [M,D]
    const float* __restrict__ x,       // [M,D]
    const float* __restrict__ Bm,      // [M,N]
    const float* __restrict__ Cm,      // [M,N]
    const float* __restrict__ A_log,   // [D,N]
    const float* __restrict__ D_skip,  // [D]
    const float* __restrict__ hin,     // [B,D,NC,N]
    float* __restrict__ y)             // [M,D]
{
    constexpr int TCt = L_ >> LNC;

    int wid = blockIdx.x * 4 + (threadIdx.x >> 6);
    int l = threadIdx.x & 63;
    int g = l >> 4, j = l & 15;
    int c = wid & (NC - 1);
    int dq = (wid >> LNC) & 31;
    int b = wid >> (LNC + 5);
    int d = dq * 4 + g;

    const float LOG2E = 1.44269504089f;
    float4 Ar = *(const float4*)&A_log[d * N_ + j * 4];
    float Ai0 = -__expf(Ar.x) * LOG2E;
    float Ai1 = -__expf(Ar.y) * LOG2E;
    float Ai2 = -__expf(Ar.z) * LOG2E;
    float Ai3 = -__expf(Ar.w) * LOG2E;
    float dsk = D_skip[d];

    float4 hv = *(const float4*)&hin[(((size_t)b * D_ + d) * NC + c) * N_ + j * 4];
    float h0 = hv.x, h1 = hv.y, h2 = hv.z, h3 = hv.w;

    size_t row0 = (size_t)b * L_ + c * TCt;
    const float* dp = delta + row0 * D_ + d;
    const float* xp = x     + row0 * D_ + d;
    const float* bp = Bm    + row0 * N_ + j * 4;
    const float* cp = Cm    + row0 * N_ + j * 4;
    float*       yp = y     + row0 * D_ + d;

    #pragma unroll 8
    for (int t = 0; t < TCt; t++) {
        float dl = dp[t * D_];
        float xv = xp[t * D_];
        float4 bv = *(const float4*)&bp[t * N_];
        float4 cv = *(const float4*)&cp[t * N_];
        float e0 = exp2f(dl * Ai0);
        float e1 = exp2f(dl * Ai1);
        float e2 = exp2f(dl * Ai2);
        float e3 = exp2f(dl * Ai3);
        float dbx = dl * xv;
        h0 = fmaf(e0, h0, dbx * bv.x);
        h1 = fmaf(e1, h1, dbx * bv.y);
        h2 = fmaf(e2, h2, dbx * bv.z);
        h3 = fmaf(e3, h3, dbx * bv.w);
        float p = fmaf(h0, cv.x, fmaf(h1, cv.y, fmaf(h2, cv.z, h3 * cv.w)));
        p += __shfl_xor(p, 1, 64);
        p += __shfl_xor(p, 2, 64);
        p += __shfl_xor(p, 4, 64);
        p += __shfl_xor(p, 8, 64);
        if (j == 0) yp[t * D_] = fmaf(dsk, xv, p);
    }
}

// ---------------------------------------------------------------------------
// Kernel 4: out = (y * silu(u_right)) @ W_down + b_down
// ---------------------------------------------------------------------------
__global__ __launch_bounds__(256) void gemm_down_mfma(
    const float* __restrict__ y,     // [M,128]
    const float* __restrict__ u,     // [M,256] right half gates
    const float* __restrict__ W,     // [128,1024]
    const float* __restrict__ bias,  // [1024]
    float* __restrict__ out)         // [M,1024]
{
    __shared__ short Al[64 * LSTR];
    __shared__ short Bl[64 * LSTR];

    int lid = blockIdx.x;            // 0..2047
    int xcd = lid & 7;
    int slot = lid >> 3;
    int bm = xcd * 16 + (slot >> 4);
    int bn = slot & 15;

    int tid = threadIdx.x;
    int w = tid >> 6, l = tid & 63;
    int lm = l & 15, q = l >> 4;
    int wm = (w & 1) * 32, wn = (w >> 1) * 32;

    f32x4 acc00 = {0,0,0,0}, acc01 = {0,0,0,0}, acc10 = {0,0,0,0}, acc11 = {0,0,0,0};

    int ar = tid >> 2, ak = (tid & 3) * 8;
    int bcol = tid & 63, bk = (tid >> 6) * 8;

    const float* Yg = y + (size_t)(bm * 64 + ar) * D_ + ak;
    const float* Ug = u + (size_t)(bm * 64 + ar) * TWO_D + D_ + ak;
    const float* Wg = W + (size_t)bn * 64 + bcol;

    for (int kt = 0; kt < 128; kt += 32) {
        float4 y0 = *(const float4*)(Yg + kt);
        float4 y1 = *(const float4*)(Yg + kt + 4);
        float4 g0 = *(const float4*)(Ug + kt);
        float4 g1 = *(const float4*)(Ug + kt + 4);
        float4 a0 = make_float4(y0.x * silu_f(g0.x), y0.y * silu_f(g0.y),
                                y0.z * silu_f(g0.z), y0.w * silu_f(g0.w));
        float4 a1 = make_float4(y1.x * silu_f(g1.x), y1.y * silu_f(g1.y),
                                y1.z * silu_f(g1.z), y1.w * silu_f(g1.w));
        *(bf16x8*)&Al[ar * LSTR + ak] = pack8(a0, a1);

        float w0 = Wg[(size_t)(kt + bk + 0) * R_];
        float w1 = Wg[(size_t)(kt + bk + 1) * R_];
        float w2 = Wg[(size_t)(kt + bk + 2) * R_];
        float w3 = Wg[(size_t)(kt + bk + 3) * R_];
        float w4 = Wg[(size_t)(kt + bk + 4) * R_];
        float w5 = Wg[(size_t)(kt + bk + 5) * R_];
        float w6 = Wg[(size_t)(kt + bk + 6) * R_];
        float w7 = Wg[(size_t)(kt + bk + 7) * R_];
        *(bf16x8*)&Bl[bcol * LSTR + bk] =
            pack8(make_float4(w0, w1, w2, w3), make_float4(w4, w5, w6, w7));

        __syncthreads();

        bf16x8 af0 = *(bf16x8*)&Al[(wm + lm) * LSTR + q * 8];
        bf16x8 af1 = *(bf16x8*)&Al[(wm + 16 + lm) * LSTR + q * 8];
        bf16x8 bf0 = *(bf16x8*)&Bl[(wn + lm) * LSTR + q * 8];
        bf16x8 bf1 = *(bf16x8*)&Bl[(wn + 16 + lm) * LSTR + q * 8];

        acc00 = __builtin_amdgcn_mfma_f32_16x16x32_bf16(af0, bf0, acc00, 0, 0, 0);
        acc01 = __builtin_amdgcn_mfma_f32_16x16x32_bf16(af0, bf1, acc01, 0, 0, 0);
        acc10 = __builtin_amdgcn_mfma_f32_16x16x32_bf16(af1, bf0, acc10, 0, 0, 0);
        acc11 = __builtin_amdgcn_mfma_f32_16x16x32_bf16(af1, bf1, acc11, 0, 0, 0);

        __syncthreads();
    }

    #pragma unroll
    for (int i = 0; i < 4; i++) {
        int r0 = bm * 64 + wm + q * 4 + i;
        int r1 = r0 + 16;
        int c0 = bn * 64 + wn + lm;
        int c1 = c0 + 16;
        out[(size_t)r0 * R_ + c0] = acc00[i] + bias[c0];
        out[(size_t)r0 * R_ + c1] = acc01[i] + bias[c1];
        out[(size_t)r1 * R_ + c0] = acc10[i] + bias[c0];
        out[(size_t)r1 * R_ + c1] = acc11[i] + bias[c1];
    }
}

// ---------------------------------------------------------------------------
extern "C" void kernel_launch(void* const* d_in, const int* in_sizes, int n_in,
                              void* d_out, int out_size, void* d_ws, size_t ws_size,
                              hipStream_t stream)
{
    const float* up_x    = (const float*)d_in[0];
    const float* W_up    = (const float*)d_in[1];
    const float* b_up    = (const float*)d_in[2];
    const float* conv_w  = (const float*)d_in[3];
    const float* conv_b  = (const float*)d_in[4];
    const float* W_delta = (const float*)d_in[5];
    const float* b_delta = (const float*)d_in[6];
    const float* W_B     = (const float*)d_in[7];
    const float* b_B     = (const float*)d_in[8];
    const float* W_C     = (const float*)d_in[9];
    const float* b_C     = (const float*)d_in[10];
    const float* A_log   = (const float*)d_in[11];
    const float* D_skip  = (const float*)d_in[12];
    const float* W_down  = (const float*)d_in[13];
    const float* b_down  = (const float*)d_in[14];

    float* out = (float*)d_out;
    float* ws  = (float*)d_ws;

    // workspace (floats), all regions DEDICATED (no aliasing):
    // u(2M) x(1M) delta(1M) Bm(.5M) Cm(.5M) y(1M) ch_aprod(2M) ch_h(2M)
    // P0(2M) P1(2M) = 14M floats = 56 MB (ws ~268 MB per harness fills)
    float* u     = ws;                          // M*2D (right half used)
    float* x     = u + (size_t)M_ * TWO_D;      // M*D
    float* delta = x + (size_t)M_ * D_;         // M*D
    float* Bm    = delta + (size_t)M_ * D_;     // M*N
    float* Cm    = Bm + (size_t)M_ * N_;        // M*N
    float* y     = Cm + (size_t)M_ * N_;        // M*D
    float* ch_aprod = y + (size_t)M_ * D_;      // B*D*NC*N (NC=64 -> 2M)
    float* ch_h  = ch_aprod + (size_t)B_ * D_ * NC * N_;
    float* P0    = ch_h + (size_t)B_ * D_ * NC * N_;   // M*2D
    float* P1    = P0 + (size_t)M_ * TWO_D;            // M*2D

    // 1. split-K up-projection
    gemm_up_splitk<<<1024, 256, 0, stream>>>(up_x, W_up, P0, P1);

    // 2. fused reduce+bias+conv+silu+gate+delta/B/C projection
    convproj_mfma<<<512, 256, 0, stream>>>(
        P0, P1, b_up, conv_w, conv_b,
        W_delta, b_delta, W_B, b_B, W_C, b_C,
        x, u, delta, Bm, Cm);

    // 3. chunked scan: summaries -> prefix -> output (separate kernels;
    //    the single cooperative-kernel variant mis-synced in round 10)
    scan_sumA<<<(B_ * (D_ / 4) * NC) / 4, 256, 0, stream>>>(
        delta, x, Bm, A_log, ch_aprod, ch_h);
    scan_prefix<<<(B_ * D_ * N_) / 256, 256, 0, stream>>>(
        ch_aprod, ch_h);
    scan_outB<<<(B_ * (D_ / 4) * NC) / 4, 256, 0, stream>>>(
        delta, x, Bm, Cm, A_log, D_skip, ch_aprod, y);

    // 4. gate + down-projection GEMM
    gemm_down_mfma<<<16 * (M_ / 64), 256, 0, stream>>>(
        y, u, W_down, b_down, out);
}